// Round 7
// baseline (5537.603 us; speedup 1.0000x reference)
//
#include <hip/hip_runtime.h>

// Inputs f32, outputs f32. Precision map (all hardware-validated):
//   - BN stats passes (k_p1, conv2/conv3 stats): f32 conv + f64 accumulate —
//     1M-pixel averages wash out rounding (R12/R14, absmax at floor).
//   - Value chain conv: f32; BN affine / feat accumulate / MLP / softmax: f64
//     (R4: cheap f32 here caused top-k rank swaps).
// Conv weights f32 (f64 weights thrash L1: R7/R9). z2 staged f32 (R11).
// R16-R19 conv3: layout/pipeline shuffles all ±6%. R20 (WIN 2160->1720):
// SGPR weights via s_load_dwordx16. R21 (4 rows/lane): flat at 1750-1780
// across occupancy 21/43/65% -> HARD FMA-PIPE FLOOR: achieved 88 TF vs
// m07's measured 103 TF practical ceiling (85%); VALUBusy 88 == FMA busy
// at the effective rate. Scheduling exhausted.
// R22: fewer FMAs — 1D Winograd F(2,3) along columns. Per lane-ic:
// 384 FMA + 12 adds (was 576 FMA) = 0.69x VALU work. Transformed weights
// [g0,(g0+g1+g2)/2,(g0-g1+g2)/2,g2] precomputed in k_cvt (exact /2) into
// W3T (393KB); Z2 shifts up, nS 4095->~4089, direct-conv fallback absorbs
// the rest. Lane = 2x2 output tile, wave = 16 oc SGPR slice (R20 idiom),
// M[16][2][4] acc fully static. Identity-checked transform.

typedef float f32x16 __attribute__((ext_vector_type(16)));

// ---- f32 weight block (float offsets into ws) ----
#define WS_W1   0
#define WS_B1   288
#define WS_W2   320
#define WS_B2   18752
#define WS_W3   18816
#define WS_B3   92544
#define WS_FCW  92672
#define WS_FCB  125440
#define WS_G1W  125696
#define WS_G1B  256768
#define WS_L1G  257280
#define WS_L1B  257792
#define WS_G2W  258304
#define WS_G2B  520448
#define WS_L2G  520960
#define WS_L2B  521472
#define WS_G3W  521984
#define WS_G3B  526080
// ---- f64 region (double offsets into ws) ----
#define D_ACC1  263044
#define D_ACC2  (D_ACC1 + 4096)
#define D_ACC3  (D_ACC2 + 8192)
#define D_FEAT  (D_ACC3 + 16384)
#define D_AFF1  (D_FEAT + 524288)
#define D_AFF2  (D_AFF1 + 64)
#define D_AFF3  (D_AFF2 + 128)
#define D_ZN    553408        // doubles zeroed from D_ACC1; region ends at byte 6,531,616
// ---- W3T: Winograd-transformed conv3 weights, after f64 region ----
// layout: [ic][ty][k][oc] -> float offset W3T_F + ic*1536 + ty*512 + k*128 + oc
#define W3T_F   1633024       // byte 6,532,096 (64B aligned); 98304 floats = 393216 B
// ---- z2 staging: first 512-aligned byte AFTER W3T ----
#define Z2_OFF_B 6925312ull

// W3 j-major layout (R18) kept for fallback kernels:
//   offset = ic*1152 + j*128 + oc

// ---------------- zero f64 accumulators ----------------
__global__ __launch_bounds__(256) void k_zero(double* __restrict__ dst){
  int i = blockIdx.x*256 + threadIdx.x;
  if(i < D_ZN) dst[i] = 0.0;
}

// ---------------- weight gather-copy (f32; W3 j-major + W3T Winograd) ----------------
struct WP { const float* p[18]; };

__global__ __launch_bounds__(256) void k_cvt(WP wp, float* __restrict__ dst){
  int s = blockIdx.y;
  int i = blockIdx.x*256 + threadIdx.x;
  if(s == 18){
    // Winograd F(2,3) weight transform for conv3: w~ = [g0,(g0+g1+g2)/2,(g0-g1+g2)/2,g2]
    if(i < 98304){
      int ic = i/1536, r = i - ic*1536;
      int ty = r>>9, r2 = r&511, k = r2>>7, oc = r2&127;
      const float* src = wp.p[4] + ((size_t)oc*64 + ic)*9 + ty*3;
      float w0=src[0], w1=src[1], w2=src[2];
      float v = (k==0) ? w0 : (k==3) ? w2 : (k==1) ? (w0+w1+w2)*0.5f : (w0-w1+w2)*0.5f;
      dst[W3T_F + i] = v;
    }
    return;
  }
  const int segn[18] = {288,32,18432,64,73728,128,32768,256,131072,512,512,512,262144,512,512,512,4096,8};
  const int sego[18] = {WS_W1,WS_B1,WS_W2,WS_B2,WS_W3,WS_B3,WS_FCW,WS_FCB,WS_G1W,WS_G1B,
                        WS_L1G,WS_L1B,WS_G2W,WS_G2B,WS_L2G,WS_L2B,WS_G3W,WS_G3B};
  if(i < segn[s]){
    if(s == 4){
      // src (OIHW flat): i = (oc*64 + ic)*9 + j  ->  j-major packed layout
      int oc = i / 576;
      int rem = i - oc*576;
      int ic = rem / 9;
      int j  = rem - ic*9;
      dst[WS_W3 + ic*1152 + j*128 + oc] = wp.p[4][i];
    } else {
      dst[sego[s]+i] = wp.p[s][i];
    }
  }
}

// ---------------- finalize BN stats ----------------
__global__ __launch_bounds__(64) void k_fin(const double* __restrict__ acc, int C,
                                            const float* __restrict__ gam, const float* __restrict__ bet,
                                            double* __restrict__ aff){
  int c = blockIdx.x, t = threadIdx.x;
  double s = acc[t*2*C + c*2];
  double q = acc[t*2*C + c*2 + 1];
  #pragma unroll
  for(int off=32;off;off>>=1){ s += __shfl_down(s,off); q += __shfl_down(q,off); }
  if(t==0){
    double m = s*(1.0/1048576.0);
    double v = q*(1.0/1048576.0) - m*m;
    double sc = (double)gam[c] / sqrt(v + 1e-5);
    aff[2*c]   = sc;
    aff[2*c+1] = (double)bet[c] - m*sc;
  }
}

// ---------------- pass 1: conv1 raw stats (f32 conv, f64 accumulate) ----------------
__global__ __launch_bounds__(256) void k_p1(const float* __restrict__ x, const float* __restrict__ wf,
                                            double* __restrict__ acc1){
  __shared__ float xp[324];
  __shared__ double red[4][32][2];
  int p = blockIdx.x, t = threadIdx.x;
  for(int i=t;i<324;i+=256) xp[i]=0.f;
  __syncthreads();
  int py=t>>4, px=t&15;
  xp[(py+1)*18 + px + 1] = x[(size_t)p*256+t];
  __syncthreads();
  float nb[9];
  #pragma unroll
  for(int j=0;j<9;j++) nb[j] = xp[(py+j/3)*18 + px + (j%3)];
  int wave=t>>6, lane=t&63;
  for(int c=0;c<32;c++){
    float a = wf[WS_B1+c];
    #pragma unroll
    for(int j=0;j<9;j++) a = fmaf(nb[j], wf[WS_W1+c*9+j], a);
    double av=(double)a;
    double s=av, q=av*av;
    #pragma unroll
    for(int off=32;off;off>>=1){ s+=__shfl_down(s,off); q+=__shfl_down(q,off); }
    if(lane==0){ red[wave][c][0]=s; red[wave][c][1]=q; }
  }
  __syncthreads();
  if(t<64){
    int c=t>>1, st=t&1;
    double v = red[0][c][st]+red[1][c][st]+red[2][c][st]+red[3][c][st];
    atomicAdd(&acc1[(p&63)*64 + c*2 + st], v);
  }
}

// ---------------- pass 2 (f32): conv1 -> bn1relu -> conv2 stats (+ z2 store) ----------------
__global__ __launch_bounds__(256) void k_p2(const float* __restrict__ x, const float* __restrict__ wf,
                                            const double* __restrict__ aff1, double* __restrict__ acc2,
                                            float* __restrict__ z2, int nS){
  __shared__ float xp[324];
  __shared__ float h1f[32*324];
  int p=blockIdx.x, t=threadIdx.x;
  for(int i=t;i<324;i+=256) xp[i]=0.f;
  for(int i=t;i<32*324;i+=256) h1f[i]=0.f;
  __syncthreads();
  int py=t>>4, px=t&15;
  xp[(py+1)*18 + px + 1] = x[(size_t)p*256+t];
  __syncthreads();
  {
    float nb[9];
    #pragma unroll
    for(int j=0;j<9;j++) nb[j] = xp[(py+j/3)*18 + px + (j%3)];
    for(int c=0;c<32;c++){
      float a = wf[WS_B1+c];
      #pragma unroll
      for(int j=0;j<9;j++) a = fmaf(nb[j], wf[WS_W1+c*9+j], a);
      h1f[c*324 + (py+1)*18 + (px+1)] = fmaxf(fmaf((float)aff1[2*c], a, (float)aff1[2*c+1]), 0.f);
    }
  }
  __syncthreads();
  int col=t&15, og=t>>4;
  bool wr = (p < nS);
  double sT[4]={0,0,0,0}, qT[4]={0,0,0,0};
  #pragma unroll 1
  for(int half=0; half<2; ++half){
    float acc[4][8];
    #pragma unroll
    for(int o=0;o<4;o++){
      float bv = wf[WS_B2 + og*4 + o];
      #pragma unroll
      for(int r=0;r<8;r++) acc[o][r]=bv;
    }
    #pragma unroll 1
    for(int ic=0; ic<32; ++ic){
      const float* wrow = wf + WS_W2 + (og*4*32 + ic)*9;
      #pragma unroll
      for(int j=0;j<9;j++){
        float w4[4];
        #pragma unroll
        for(int o=0;o<4;o++) w4[o] = wrow[o*288 + j];
        int dy=j/3, dx=j%3;
        #pragma unroll
        for(int r=0;r<8;r++){
          float m = h1f[ic*324 + (half*8 + r + dy)*18 + col + dx];
          #pragma unroll
          for(int o=0;o<4;o++) acc[o][r] = fmaf(m, w4[o], acc[o][r]);
        }
      }
    }
    #pragma unroll
    for(int o=0;o<4;o++){
      #pragma unroll
      for(int r=0;r<8;r++){ double v=(double)acc[o][r]; sT[o]+=v; qT[o]+=v*v; }
      if(wr){
        int c = og*4+o;
        #pragma unroll
        for(int r=0;r<8;r++) z2[((size_t)p*64+c)*256 + (half*8+r)*16 + col] = acc[o][r];
      }
    }
  }
  #pragma unroll
  for(int o=0;o<4;o++){
    double s=sT[o], q=qT[o];
    #pragma unroll
    for(int off=8;off;off>>=1){ s+=__shfl_down(s,off,16); q+=__shfl_down(q,off,16); }
    if(col==0){
      int c = og*4+o;
      atomicAdd(&acc2[(p&63)*128 + c*2 + 0], s);
      atomicAdd(&acc2[(p&63)*128 + c*2 + 1], q);
    }
  }
}

// ========= STAGED conv3 stats (f32, 1D Winograd F(2,3)): 512 thr, 1 block/patch =========
// lane l = t&63: cp = l&7 (out cols 2cp,2cp+1), rg = l>>3 (out rows 2rg,2rg+1);
// wave wv = t>>6 owns oc [wv*16, wv*16+16) via SGPR weight slice.
__global__ __launch_bounds__(512) void k_cs(const float* __restrict__ wf, const double* __restrict__ aff2,
                                            double* __restrict__ acc3, const float* __restrict__ z2){
  __shared__ float h2S[32*360];   // [32 ch][18 rows][20-col stride], 46080 B
  int p=blockIdx.x, t=threadIdx.x;
  for(int i=t;i<11520;i+=512) h2S[i]=0.f;   // halo rows/cols stay 0 across both halves
  int l=t&63, cp=l&7, rg=l>>3;
  int wv = __builtin_amdgcn_readfirstlane(t>>6);
  float M[16][2][4];              // Winograd-domain acc: [oc][out-row][k]
  #pragma unroll
  for(int o=0;o<16;o++){
    #pragma unroll
    for(int orr=0;orr<2;orr++){
      #pragma unroll
      for(int k=0;k<4;k++) M[o][orr][k]=0.f;
    }
  }
  const f32x16* WT = reinterpret_cast<const f32x16*>(wf + W3T_F + wv*16); // row stride 128 fl = 8 vec
  #pragma unroll 1
  for(int half=0; half<2; ++half){
    __syncthreads();              // zero done (h0) / previous half consumed (h1)
    for(int i=t;i<8192;i+=512){   // 32 ch x 16 rows x 16 cols (pure shifts)
      int ch2 = i>>8, rem = i&255, gr = rem>>4, c2 = rem&15;
      int ch = half*32 + ch2;
      float zv = z2[((size_t)p*64+ch)*256 + gr*16 + c2];
      h2S[ch2*360 + (gr+1)*20 + c2+1] = fmaxf(fmaf((float)aff2[2*ch], zv, (float)aff2[2*ch+1]), 0.f);
    }
    __syncthreads();
    #pragma unroll 1
    for(int ic2=0; ic2<32; ++ic2){
      int ic = half*32 + ic2;
      // input transform: 4 rows (in rows 2rg-1..2rg+2 -> LDS rows 2rg..2rg+3), 4 cols
      float vt[4][4];
      #pragma unroll
      for(int lr=0; lr<4; ++lr){
        float d0 = h2S[ic2*360 + (2*rg+lr)*20 + 2*cp + 0];
        float d1 = h2S[ic2*360 + (2*rg+lr)*20 + 2*cp + 1];
        float d2 = h2S[ic2*360 + (2*rg+lr)*20 + 2*cp + 2];
        float d3 = h2S[ic2*360 + (2*rg+lr)*20 + 2*cp + 3];
        vt[lr][0]=d0-d2; vt[lr][1]=d1+d2; vt[lr][2]=d2-d1; vt[lr][3]=d1-d3;
      }
      #pragma unroll
      for(int ty=0;ty<3;ty++){
        f32x16 w0 = WT[(size_t)((ic*3+ty)*4+0)*8];   // uniform -> s_load_dwordx16
        f32x16 w1 = WT[(size_t)((ic*3+ty)*4+1)*8];
        f32x16 w2 = WT[(size_t)((ic*3+ty)*4+2)*8];
        f32x16 w3 = WT[(size_t)((ic*3+ty)*4+3)*8];
        #pragma unroll
        for(int o=0;o<16;o++){
          #pragma unroll
          for(int orr=0;orr<2;orr++){
            M[o][orr][0] = fmaf(vt[orr+ty][0], w0[o], M[o][orr][0]);
            M[o][orr][1] = fmaf(vt[orr+ty][1], w1[o], M[o][orr][1]);
            M[o][orr][2] = fmaf(vt[orr+ty][2], w2[o], M[o][orr][2]);
            M[o][orr][3] = fmaf(vt[orr+ty][3], w3[o], M[o][orr][3]);
          }
        }
      }
    }
  }
  // output transform + stats
  #pragma unroll
  for(int o=0;o<16;o++){
    float bv = wf[WS_B3 + wv*16 + o];
    float y00 = M[o][0][0]+M[o][0][1]+M[o][0][2] + bv;
    float y01 = M[o][0][1]-M[o][0][2]-M[o][0][3] + bv;
    float y10 = M[o][1][0]+M[o][1][1]+M[o][1][2] + bv;
    float y11 = M[o][1][1]-M[o][1][2]-M[o][1][3] + bv;
    double s  = (double)y00+(double)y01+(double)y10+(double)y11;
    double q2 = (double)y00*(double)y00+(double)y01*(double)y01
              + (double)y10*(double)y10+(double)y11*(double)y11;
    #pragma unroll
    for(int off=32;off;off>>=1){ s += __shfl_down(s,off); q2 += __shfl_down(q2,off); }
    if((t&63)==0){
      int c = wv*16+o;
      atomicAdd(&acc3[(p&63)*256 + c*2 + 0], s);
      atomicAdd(&acc3[(p&63)*256 + c*2 + 1], q2);
    }
  }
}

// ========= STAGED conv3 feat (f32 Winograd conv, f64 accumulate): same structure =========
__global__ __launch_bounds__(512) void k_cf(const float* __restrict__ wf, const double* __restrict__ aff2,
                                            const double* __restrict__ aff3, double* __restrict__ feat,
                                            const float* __restrict__ z2){
  __shared__ float h2S[32*360];
  int p=blockIdx.x, t=threadIdx.x;
  for(int i=t;i<11520;i+=512) h2S[i]=0.f;
  int l=t&63, cp=l&7, rg=l>>3;
  int wv = __builtin_amdgcn_readfirstlane(t>>6);
  float M[16][2][4];
  #pragma unroll
  for(int o=0;o<16;o++){
    #pragma unroll
    for(int orr=0;orr<2;orr++){
      #pragma unroll
      for(int k=0;k<4;k++) M[o][orr][k]=0.f;
    }
  }
  const f32x16* WT = reinterpret_cast<const f32x16*>(wf + W3T_F + wv*16);
  #pragma unroll 1
  for(int half=0; half<2; ++half){
    __syncthreads();
    for(int i=t;i<8192;i+=512){
      int ch2 = i>>8, rem = i&255, gr = rem>>4, c2 = rem&15;
      int ch = half*32 + ch2;
      float zv = z2[((size_t)p*64+ch)*256 + gr*16 + c2];
      h2S[ch2*360 + (gr+1)*20 + c2+1] = fmaxf(fmaf((float)aff2[2*ch], zv, (float)aff2[2*ch+1]), 0.f);
    }
    __syncthreads();
    #pragma unroll 1
    for(int ic2=0; ic2<32; ++ic2){
      int ic = half*32 + ic2;
      float vt[4][4];
      #pragma unroll
      for(int lr=0; lr<4; ++lr){
        float d0 = h2S[ic2*360 + (2*rg+lr)*20 + 2*cp + 0];
        float d1 = h2S[ic2*360 + (2*rg+lr)*20 + 2*cp + 1];
        float d2 = h2S[ic2*360 + (2*rg+lr)*20 + 2*cp + 2];
        float d3 = h2S[ic2*360 + (2*rg+lr)*20 + 2*cp + 3];
        vt[lr][0]=d0-d2; vt[lr][1]=d1+d2; vt[lr][2]=d2-d1; vt[lr][3]=d1-d3;
      }
      #pragma unroll
      for(int ty=0;ty<3;ty++){
        f32x16 w0 = WT[(size_t)((ic*3+ty)*4+0)*8];
        f32x16 w1 = WT[(size_t)((ic*3+ty)*4+1)*8];
        f32x16 w2 = WT[(size_t)((ic*3+ty)*4+2)*8];
        f32x16 w3 = WT[(size_t)((ic*3+ty)*4+3)*8];
        #pragma unroll
        for(int o=0;o<16;o++){
          #pragma unroll
          for(int orr=0;orr<2;orr++){
            M[o][orr][0] = fmaf(vt[orr+ty][0], w0[o], M[o][orr][0]);
            M[o][orr][1] = fmaf(vt[orr+ty][1], w1[o], M[o][orr][1]);
            M[o][orr][2] = fmaf(vt[orr+ty][2], w2[o], M[o][orr][2]);
            M[o][orr][3] = fmaf(vt[orr+ty][3], w3[o], M[o][orr][3]);
          }
        }
      }
    }
  }
  #pragma unroll
  for(int o=0;o<16;o++){
    int c = wv*16+o;
    float bv = wf[WS_B3 + c];
    float sc=(float)aff3[2*c], sh=(float)aff3[2*c+1];
    float y00 = M[o][0][0]+M[o][0][1]+M[o][0][2] + bv;
    float y01 = M[o][0][1]-M[o][0][2]-M[o][0][3] + bv;
    float y10 = M[o][1][0]+M[o][1][1]+M[o][1][2] + bv;
    float y11 = M[o][1][1]-M[o][1][2]-M[o][1][3] + bv;
    double sv = (double)fmaxf(fmaf(sc, y00, sh), 0.f)
              + (double)fmaxf(fmaf(sc, y01, sh), 0.f)
              + (double)fmaxf(fmaf(sc, y10, sh), 0.f)
              + (double)fmaxf(fmaf(sc, y11, sh), 0.f);
    #pragma unroll
    for(int off=32;off;off>>=1) sv += __shfl_down(sv,off);
    if((t&63)==0) atomicAdd(&feat[(size_t)p*128 + c], sv);
  }
}

// ========= FALLBACK recompute conv3 stats (f32, direct conv), patches p0.. =========
__global__ __launch_bounds__(256) void k_stat3(const float* __restrict__ x, const float* __restrict__ wf,
                                               const double* __restrict__ aff1, const double* __restrict__ aff2,
                                               double* __restrict__ acc3, int p0){
  __shared__ float xp[324];
  __shared__ float h1S[32*144];
  __shared__ float h2S[64*108];
  int bid=blockIdx.x, t=threadIdx.x;
  int p = p0 + (bid>>2), r0 = (bid&3)*4;
  for(int i=t;i<64*108;i+=256) h2S[i]=0.f;
  for(int i=t;i<324;i+=256) xp[i]=0.f;
  for(int i=t;i<32*144;i+=256) h1S[i]=0.f;
  __syncthreads();
  { int py=t>>4, px=t&15; xp[(py+1)*18 + px + 1] = x[(size_t)p*256+t]; }
  __syncthreads();
  {
    int rr=t>>5, cw=t&31, col=cw&15, half=cw>>4;
    int p1 = r0-1+rr;
    if(p1>=1 && p1<=16){
      float nb[9];
      #pragma unroll
      for(int j=0;j<9;j++) nb[j] = xp[(p1-1+j/3)*18 + col + (j%3)];
      for(int k=0;k<16;k++){
        int c = half*16+k;
        float a = wf[WS_B1+c];
        #pragma unroll
        for(int j=0;j<9;j++) a = fmaf(nb[j], wf[WS_W1+c*9+j], a);
        h1S[c*144 + rr*18 + col+1] = fmaxf((float)aff1[2*c]*a + (float)aff1[2*c+1], 0.f);
      }
    }
  }
  __syncthreads();
  {
    int col=t&15, g=t>>4;
    float a24[4][6];
    #pragma unroll
    for(int o=0;o<4;o++){
      float bv = wf[WS_B2+g*4+o];
      #pragma unroll
      for(int b2=0;b2<6;b2++) a24[o][b2] = bv;
    }
    #pragma unroll 1
    for(int ic=0;ic<32;ic++){
      const float* wrow = wf + WS_W2 + (g*4*32 + ic)*9;
      #pragma unroll
      for(int j=0;j<9;j++){
        float w4[4];
        #pragma unroll
        for(int o=0;o<4;o++) w4[o] = wrow[o*288 + j];
        int dy=j/3, dx=j%3;
        #pragma unroll
        for(int b2=0;b2<6;b2++){
          float m = h1S[ic*144 + (b2+dy)*18 + col + dx];
          #pragma unroll
          for(int o=0;o<4;o++) a24[o][b2] = fmaf(m, w4[o], a24[o][b2]);
        }
      }
    }
    #pragma unroll
    for(int b2=0;b2<6;b2++){
      int p2 = r0+b2;
      if(p2>=1 && p2<=16){
        #pragma unroll
        for(int o=0;o<4;o++){
          int c=g*4+o;
          h2S[c*108 + b2*18 + col+1] = fmaxf((float)aff2[2*c]*a24[o][b2] + (float)aff2[2*c+1], 0.f);
        }
      }
    }
  }
  __syncthreads();
  {
    int col = t & 15, og = t >> 4;
    float acc[8][4];
    #pragma unroll
    for(int o=0;o<8;o++){
      float bv = wf[WS_B3 + og*8 + o];
      #pragma unroll
      for(int r=0;r<4;r++) acc[o][r] = bv;
    }
    #pragma unroll 1
    for(int ic=0; ic<64; ++ic){
      float a[6][3];
      #pragma unroll
      for(int rr=0; rr<6; ++rr){
        #pragma unroll
        for(int dx=0; dx<3; ++dx) a[rr][dx] = h2S[ic*108 + rr*18 + col + dx];
      }
      const float* wrow = wf + WS_W3 + ic*1152;   // j-major layout (R18)
      #pragma unroll
      for(int o=0;o<8;o++){
        #pragma unroll
        for(int j=0;j<9;j++){
          float w = wrow[j*128 + og*8 + o];
          #pragma unroll
          for(int r=0;r<4;r++) acc[o][r] = fmaf(a[r + j/3][j%3], w, acc[o][r]);
        }
      }
    }
    #pragma unroll
    for(int o=0;o<8;o++){
      double s=0.0, q=0.0;
      #pragma unroll
      for(int r=0;r<4;r++){ double v=(double)acc[o][r]; s+=v; q+=v*v; }
      #pragma unroll
      for(int off=8; off; off>>=1){ s += __shfl_down(s, off, 16); q += __shfl_down(q, off, 16); }
      if(col==0){
        int c = og*8+o;
        atomicAdd(&acc3[(bid&63)*256 + c*2 + 0], s);
        atomicAdd(&acc3[(bid&63)*256 + c*2 + 1], q);
      }
    }
  }
}

// ========= FALLBACK recompute conv3 feat (f32 direct conv, f64 accumulate), patches p0.. =========
__global__ __launch_bounds__(256) void k_p34(const float* __restrict__ x, const float* __restrict__ wf,
                                             const double* __restrict__ aff1, const double* __restrict__ aff2,
                                             const double* __restrict__ aff3, double* __restrict__ outp,
                                             int p0){
  __shared__ float xp[324];
  __shared__ float h1S[32*144];
  __shared__ float h2S[64*108];
  int bid=blockIdx.x, t=threadIdx.x;
  int p = p0 + (bid>>2), r0 = (bid&3)*4;
  for(int i=t;i<64*108;i+=256) h2S[i]=0.f;
  for(int i=t;i<324;i+=256) xp[i]=0.f;
  for(int i=t;i<32*144;i+=256) h1S[i]=0.f;
  __syncthreads();
  { int py=t>>4, px=t&15; xp[(py+1)*18 + px + 1] = x[(size_t)p*256+t]; }
  __syncthreads();
  {
    int rr=t>>5, cw=t&31, col=cw&15, half=cw>>4;
    int p1 = r0-1+rr;
    if(p1>=1 && p1<=16){
      float nb[9];
      #pragma unroll
      for(int j=0;j<9;j++) nb[j] = xp[(p1-1+j/3)*18 + col + (j%3)];
      for(int k=0;k<16;k++){
        int c = half*16+k;
        float a = wf[WS_B1+c];
        #pragma unroll
        for(int j=0;j<9;j++) a = fmaf(nb[j], wf[WS_W1+c*9+j], a);
        h1S[c*144 + rr*18 + col+1] = fmaxf((float)aff1[2*c]*a + (float)aff1[2*c+1], 0.f);
      }
    }
  }
  __syncthreads();
  {
    int col=t&15, g=t>>4;
    float a24[4][6];
    #pragma unroll
    for(int o=0;o<4;o++){
      float bv = wf[WS_B2+g*4+o];
      #pragma unroll
      for(int b2=0;b2<6;b2++) a24[o][b2] = bv;
    }
    #pragma unroll 1
    for(int ic=0;ic<32;ic++){
      const float* wrow = wf + WS_W2 + (g*4*32 + ic)*9;
      #pragma unroll
      for(int j=0;j<9;j++){
        float w4[4];
        #pragma unroll
        for(int o=0;o<4;o++) w4[o] = wrow[o*288 + j];
        int dy=j/3, dx=j%3;
        #pragma unroll
        for(int b2=0;b2<6;b2++){
          float m = h1S[ic*144 + (b2+dy)*18 + col + dx];
          #pragma unroll
          for(int o=0;o<4;o++) a24[o][b2] = fmaf(m, w4[o], a24[o][b2]);
        }
      }
    }
    #pragma unroll
    for(int b2=0;b2<6;b2++){
      int p2 = r0+b2;
      if(p2>=1 && p2<=16){
        #pragma unroll
        for(int o=0;o<4;o++){
          int c=g*4+o;
          h2S[c*108 + b2*18 + col+1] = fmaxf((float)aff2[2*c]*a24[o][b2] + (float)aff2[2*c+1], 0.f);
        }
      }
    }
  }
  __syncthreads();
  {
    int col = t & 15, og = t >> 4;
    float acc[8][4];
    #pragma unroll
    for(int o=0;o<8;o++){
      float bv = wf[WS_B3 + og*8 + o];
      #pragma unroll
      for(int r=0;r<4;r++) acc[o][r] = bv;
    }
    #pragma unroll 1
    for(int ic=0; ic<64; ++ic){
      float a[6][3];
      #pragma unroll
      for(int rr=0; rr<6; ++rr){
        #pragma unroll
        for(int dx=0; dx<3; ++dx) a[rr][dx] = h2S[ic*108 + rr*18 + col + dx];
      }
      const float* wrow = wf + WS_W3 + ic*1152;   // j-major layout (R18)
      #pragma unroll
      for(int o=0;o<8;o++){
        #pragma unroll
        for(int j=0;j<9;j++){
          float w = wrow[j*128 + og*8 + o];
          #pragma unroll
          for(int r=0;r<4;r++) acc[o][r] = fmaf(a[r + j/3][j%3], w, acc[o][r]);
        }
      }
    }
    #pragma unroll
    for(int o=0;o<8;o++){
      int c = og*8+o;
      float sc=(float)aff3[2*c], sh=(float)aff3[2*c+1];
      double s = 0.0;
      #pragma unroll
      for(int r=0;r<4;r++) s += (double)fmaxf(fmaf(sc, acc[o][r], sh), 0.f);
      #pragma unroll
      for(int off=8; off; off>>=1) s += __shfl_down(s, off, 16);
      if(col==0) atomicAdd(&outp[(size_t)p*128 + c], s);
    }
  }
}

// ---------------- LN + relu on [4][512] f64 LDS buffer ----------------
__device__ __forceinline__ void ln_relu4(double* buf, const float* __restrict__ g, const float* __restrict__ b,
                                         double* lnm, double* lnr, int t){
  int r=t>>6, j=t&63;
  double s=0.0, q=0.0;
  for(int k=j;k<512;k+=64){ double v=buf[r*512+k]; s+=v; q+=v*v; }
  #pragma unroll
  for(int off=32;off;off>>=1){ s+=__shfl_down(s,off); q+=__shfl_down(q,off); }
  if(j==0){
    double m = s*(1.0/512.0);
    double v = q*(1.0/512.0) - m*m;
    lnm[r]=m; lnr[r]=1.0/sqrt(v + 1e-5);
  }
  __syncthreads();
  for(int i=t;i<2048;i+=256){
    int r2=i>>9, k=i&511;
    double v=(buf[i]-lnm[r2])*lnr[r2]*(double)g[k]+(double)b[k];
    buf[i]=fmax(v,0.0);
  }
  __syncthreads();
}

// ---------------- MLP head (f64): feat -> assignment f32 (4 rows/block; R12 version) ----------------
__global__ __launch_bounds__(256) void k_mlp(const float* __restrict__ wf, const double* __restrict__ feat,
                                             float* __restrict__ assign_out){
  int r0 = blockIdx.x*4, t = threadIdx.x;
  __shared__ double f0[4*128];
  __shared__ double f1[4*256];
  __shared__ double f2[4*512];
  __shared__ double f3[4*512];
  __shared__ double lnm[4], lnr[4];
  __shared__ double lg[4][8];

  for(int i=t;i<512;i+=256) f0[i] = feat[(size_t)r0*128 + i] * (1.0/256.0);
  __syncthreads();
  {
    double acc[4];
    double bv = (double)wf[WS_FCB + t];
    #pragma unroll
    for(int r=0;r<4;r++) acc[r]=bv;
    for(int k=0;k<128;k++){
      double wv = (double)wf[WS_FCW + t*128 + k];
      #pragma unroll
      for(int r=0;r<4;r++) acc[r]=fma(wv, f0[r*128+k], acc[r]);
    }
    #pragma unroll
    for(int r=0;r<4;r++) f1[r*256+t]=acc[r];
  }
  __syncthreads();
  for(int half=0;half<2;half++){
    int i=t+(half<<8);
    double acc[4];
    double bv=(double)wf[WS_G1B+i];
    #pragma unroll
    for(int r=0;r<4;r++) acc[r]=bv;
    for(int k=0;k<256;k++){
      double wv=(double)wf[WS_G1W + i*256 + k];
      #pragma unroll
      for(int r=0;r<4;r++) acc[r]=fma(wv, f1[r*256+k], acc[r]);
    }
    #pragma unroll
    for(int r=0;r<4;r++) f2[r*512+i]=acc[r];
  }
  __syncthreads();
  ln_relu4(f2, wf+WS_L1G, wf+WS_L1B, lnm, lnr, t);
  for(int half=0;half<2;half++){
    int i=t+(half<<8);
    double acc[4];
    double bv=(double)wf[WS_G2B+i];
    #pragma unroll
    for(int r=0;r<4;r++) acc[r]=bv;
    for(int k=0;k<512;k++){
      double wv=(double)wf[WS_G2W + i*512 + k];
      #pragma unroll
      for(int r=0;r<4;r++) acc[r]=fma(wv, f2[r*512+k], acc[r]);
    }
    #pragma unroll
    for(int r=0;r<4;r++) f3[r*512+i]=acc[r];
  }
  __syncthreads();
  ln_relu4(f3, wf+WS_L2G, wf+WS_L2B, lnm, lnr, t);
  {
    int r=t>>6, j=t&63;
    double pl[8];
    #pragma unroll
    for(int g=0;g<8;g++){
      double s=0.0;
      for(int k=j;k<512;k+=64) s = fma(f3[r*512+k], (double)wf[WS_G3W + g*512 + k], s);
      pl[g]=s;
    }
    #pragma unroll
    for(int off=32;off;off>>=1){
      #pragma unroll
      for(int g=0;g<8;g++) pl[g] += __shfl_down(pl[g], off);
    }
    if(j==0){
      #pragma unroll
      for(int g=0;g<8;g++) lg[r][g] = (pl[g] + (double)wf[WS_G3B+g]) * 2.0; // /TEMP
    }
  }
  __syncthreads();
  if(t<4){
    double m=-1e300;
    #pragma unroll
    for(int g=0;g<8;g++) m = fmax(m, lg[t][g]);
    double e[8], s=0.0;
    #pragma unroll
    for(int g=0;g<8;g++){ e[g]=exp(lg[t][g]-m); s+=e[g]; }
    double inv = 1.0/s;
    int row = r0 + t;
    #pragma unroll
    for(int g=0;g<8;g++) assign_out[row*8+g] = (float)(e[g]*inv);
  }
}

// ---------------- top-32 per (b,g) + gather*scale ----------------
__global__ __launch_bounds__(256) void k_topk(const float* __restrict__ assign, const float* __restrict__ x,
                                              float* __restrict__ out){
  int b = blockIdx.x >> 3, g = blockIdx.x & 7, t = threadIdx.x;
  __shared__ float v[256];
  __shared__ int   id[256];
  v[t] = assign[(b*256+t)*8 + g];
  id[t] = t;
  __syncthreads();
  for(int k=2;k<=256;k<<=1){
    for(int j=k>>1;j>0;j>>=1){
      int ixj = t ^ j;
      if(ixj > t){
        float va=v[t], vb=v[ixj];
        int ia=id[t], ib=id[ixj];
        bool aBefore = (va > vb) || (va == vb && ia < ib);
        bool up = ((t & k) == 0);
        if(up != aBefore){ v[t]=vb; v[ixj]=va; id[t]=ib; id[ixj]=ia; }
      }
      __syncthreads();
    }
  }
  __shared__ float tv[32];
  __shared__ int   ti[32];
  if(t<32){ tv[t]=v[t]; ti[t]=id[t]; }
  __syncthreads();
  const float* xb = x + (size_t)b*65536;
  float* ob = out + (size_t)(b*8+g)*8192;
  for(int i=t;i<8192;i+=256){
    int k=i>>8, pix=i&255;
    ob[i] = tv[k] * xb[ti[k]*256 + pix];
  }
}

// ---------------- launcher ----------------
extern "C" void kernel_launch(void* const* d_in, const int* in_sizes, int n_in,
                              void* d_out, int out_size, void* d_ws, size_t ws_size,
                              hipStream_t stream){
  const float* x = (const float*)d_in[0];
  float*  ws  = (float*)d_ws;
  double* dws = (double*)d_ws;
  float* out = (float*)d_out;
  float* assign_out = out + 1048576;
  float* z2 = (float*)((char*)d_ws + Z2_OFF_B);

  int nS = 0;
  if(ws_size > Z2_OFF_B + 65536){
    unsigned long long avail = (unsigned long long)ws_size - Z2_OFF_B;
    unsigned long long n = avail / 65536ull;
    nS = (n > 4096ull) ? 4096 : (int)n;
  }
  int nR = 4096 - nS;

  const float* g1=(const float*)d_in[3];  const float* b1=(const float*)d_in[4];
  const float* g2=(const float*)d_in[7];  const float* b2=(const float*)d_in[8];
  const float* g3=(const float*)d_in[11]; const float* b3=(const float*)d_in[12];

  WP wp;
  const int map[18] = {1,2,5,6,9,10,13,14,15,16,17,18,19,20,21,22,23,24};
  for(int i=0;i<18;i++) wp.p[i] = (const float*)d_in[map[i]];

  k_zero <<<2162, 256, 0, stream>>>(dws + D_ACC1);
  k_cvt  <<<dim3(1024,19), 256, 0, stream>>>(wp, ws);
  k_p1   <<<4096, 256, 0, stream>>>(x, ws, dws+D_ACC1);
  k_fin  <<<32, 64, 0, stream>>>(dws+D_ACC1, 32, g1, b1, dws+D_AFF1);
  k_p2   <<<4096, 256, 0, stream>>>(x, ws, dws+D_AFF1, dws+D_ACC2, z2, nS);
  k_fin  <<<64, 64, 0, stream>>>(dws+D_ACC2, 64, g2, b2, dws+D_AFF2);
  if(nS > 0) k_cs   <<<nS, 512, 0, stream>>>(ws, dws+D_AFF2, dws+D_ACC3, z2);
  if(nR > 0) k_stat3<<<4*nR, 256, 0, stream>>>(x, ws, dws+D_AFF1, dws+D_AFF2, dws+D_ACC3, nS);
  k_fin  <<<128, 64, 0, stream>>>(dws+D_ACC3, 128, g3, b3, dws+D_AFF3);
  if(nS > 0) k_cf  <<<nS, 512, 0, stream>>>(ws, dws+D_AFF2, dws+D_AFF3, dws+D_FEAT, z2);
  if(nR > 0) k_p34 <<<4*nR, 256, 0, stream>>>(x, ws, dws+D_AFF1, dws+D_AFF2, dws+D_AFF3, dws+D_FEAT, nS);
  k_mlp  <<<1024, 256, 0, stream>>>(ws, dws+D_FEAT, assign_out);
  k_topk <<<128, 256, 0, stream>>>(assign_out, x, out);
}

// Round 9
// 4006.837 us; speedup vs baseline: 1.3820x; 1.3820x over previous
//
#include <hip/hip_runtime.h>

// Inputs f32, outputs f32. Precision map (all hardware-validated):
//   - BN stats passes (k_p1, conv2/conv3 stats): f32 conv + f64 accumulate —
//     1M-pixel averages wash out rounding (R12/R14, absmax at floor).
//   - Value chain conv: f32; BN affine / feat accumulate / MLP / softmax: f64
//     (R4: cheap f32 here caused top-k rank swaps).
// Conv weights f32 (f64 weights thrash L1: R7/R9). z2 staged f32 (R11).
// R16-R19 conv3: layout/pipeline shuffles all ±6%. R20 (WIN 2160->1720/pass):
// wave-uniform 16-oc slice -> s_load_dwordx16 weights as SGPR FMA operands,
// ONE 16-SGPR group live at a time; 88% duty vs measured 103-TF FMA ceiling.
// R21 (4 rows/lane): flat. R22 (Winograd F(2,3)): REGRESSED 1750->2360 —
// FMA work did drop 0.78x as predicted, but 4 concurrent 16-SGPR weight
// groups per tap-row exceed the prefetch budget -> s_load latency exposed,
// duty 88->51%. Conv3 is at its practical roofline with the R20 schedule.
// R23: revert conv3 to R20 verbatim; port the R20 idiom to k_p2's conv2
// (was per-thread strided scalar weights): W2T j-major [ic][j][oc] packed
// at W2T_F, wave=16oc, lane=(col, 4-row group), acc[16][4]. Per-element
// FMA order identical -> z2 bit-identical; only f64 stats order changes.
// R24: identical resubmit — R23 bench died to container infra (no verdict);
// diff audited clean for hang/fault classes (regions, alignment, barriers,
// lane coverage, nS edge with validated fallback path).

typedef float f32x16 __attribute__((ext_vector_type(16)));

// ---- f32 weight block (float offsets into ws) ----
#define WS_W1   0
#define WS_B1   288
#define WS_W2   320
#define WS_B2   18752
#define WS_W3   18816
#define WS_B3   92544
#define WS_FCW  92672
#define WS_FCB  125440
#define WS_G1W  125696
#define WS_G1B  256768
#define WS_L1G  257280
#define WS_L1B  257792
#define WS_G2W  258304
#define WS_G2B  520448
#define WS_L2G  520960
#define WS_L2B  521472
#define WS_G3W  521984
#define WS_G3B  526080
// ---- f64 region (double offsets into ws) ----
#define D_ACC1  263044
#define D_ACC2  (D_ACC1 + 4096)
#define D_ACC3  (D_ACC2 + 8192)
#define D_FEAT  (D_ACC3 + 16384)
#define D_AFF1  (D_FEAT + 524288)
#define D_AFF2  (D_AFF1 + 64)
#define D_AFF3  (D_AFF2 + 128)
#define D_ZN    553408        // doubles zeroed from D_ACC1; region ends at byte 6,531,616
// ---- W2T: j-major conv2 weights [ic][j][oc], after f64 region ----
// float offset W2T_F + ic*576 + j*64 + oc ; 18432 floats, 64B-aligned base
#define W2T_F   1632912       // byte 6,531,648
// ---- z2 staging: first 512-aligned byte AFTER W2T ----
#define Z2_OFF_B 6605824ull

// W3 j-major layout (R18): offset = ic*1152 + j*128 + oc  (max 73727).
// Wave wv owns oc [wv*16, wv*16+16): one 64-B-aligned float16 per (ic,j)
// at WS_W3 + ic*1152 + j*128 + wv*16 — wave-uniform => s_load.

// ---------------- zero f64 accumulators ----------------
__global__ __launch_bounds__(256) void k_zero(double* __restrict__ dst){
  int i = blockIdx.x*256 + threadIdx.x;
  if(i < D_ZN) dst[i] = 0.0;
}

// ---------------- weight gather-copy (f32; W3 j-major, W2T j-major) ----------------
struct WP { const float* p[18]; };

__global__ __launch_bounds__(256) void k_cvt(WP wp, float* __restrict__ dst){
  int s = blockIdx.y;
  int i = blockIdx.x*256 + threadIdx.x;
  if(s == 18){
    // conv2 weights (64,32,3,3): i = (oc*32+ic)*9 + j -> j-major [ic][j][oc]
    if(i < 18432){
      int oc = i / 288;
      int rem = i - oc*288;
      int ic = rem / 9;
      int j  = rem - ic*9;
      dst[W2T_F + ic*576 + j*64 + oc] = wp.p[2][i];
    }
    return;
  }
  const int segn[18] = {288,32,18432,64,73728,128,32768,256,131072,512,512,512,262144,512,512,512,4096,8};
  const int sego[18] = {WS_W1,WS_B1,WS_W2,WS_B2,WS_W3,WS_B3,WS_FCW,WS_FCB,WS_G1W,WS_G1B,
                        WS_L1G,WS_L1B,WS_G2W,WS_G2B,WS_L2G,WS_L2B,WS_G3W,WS_G3B};
  if(i < segn[s]){
    if(s == 4){
      // src (OIHW flat): i = (oc*64 + ic)*9 + j  ->  j-major packed layout
      int oc = i / 576;
      int rem = i - oc*576;
      int ic = rem / 9;
      int j  = rem - ic*9;
      dst[WS_W3 + ic*1152 + j*128 + oc] = wp.p[4][i];
    } else {
      dst[sego[s]+i] = wp.p[s][i];
    }
  }
}

// ---------------- finalize BN stats ----------------
__global__ __launch_bounds__(64) void k_fin(const double* __restrict__ acc, int C,
                                            const float* __restrict__ gam, const float* __restrict__ bet,
                                            double* __restrict__ aff){
  int c = blockIdx.x, t = threadIdx.x;
  double s = acc[t*2*C + c*2];
  double q = acc[t*2*C + c*2 + 1];
  #pragma unroll
  for(int off=32;off;off>>=1){ s += __shfl_down(s,off); q += __shfl_down(q,off); }
  if(t==0){
    double m = s*(1.0/1048576.0);
    double v = q*(1.0/1048576.0) - m*m;
    double sc = (double)gam[c] / sqrt(v + 1e-5);
    aff[2*c]   = sc;
    aff[2*c+1] = (double)bet[c] - m*sc;
  }
}

// ---------------- pass 1: conv1 raw stats (f32 conv, f64 accumulate) ----------------
__global__ __launch_bounds__(256) void k_p1(const float* __restrict__ x, const float* __restrict__ wf,
                                            double* __restrict__ acc1){
  __shared__ float xp[324];
  __shared__ double red[4][32][2];
  int p = blockIdx.x, t = threadIdx.x;
  for(int i=t;i<324;i+=256) xp[i]=0.f;
  __syncthreads();
  int py=t>>4, px=t&15;
  xp[(py+1)*18 + px + 1] = x[(size_t)p*256+t];
  __syncthreads();
  float nb[9];
  #pragma unroll
  for(int j=0;j<9;j++) nb[j] = xp[(py+j/3)*18 + px + (j%3)];
  int wave=t>>6, lane=t&63;
  for(int c=0;c<32;c++){
    float a = wf[WS_B1+c];
    #pragma unroll
    for(int j=0;j<9;j++) a = fmaf(nb[j], wf[WS_W1+c*9+j], a);
    double av=(double)a;
    double s=av, q=av*av;
    #pragma unroll
    for(int off=32;off;off>>=1){ s+=__shfl_down(s,off); q+=__shfl_down(q,off); }
    if(lane==0){ red[wave][c][0]=s; red[wave][c][1]=q; }
  }
  __syncthreads();
  if(t<64){
    int c=t>>1, st=t&1;
    double v = red[0][c][st]+red[1][c][st]+red[2][c][st]+red[3][c][st];
    atomicAdd(&acc1[(p&63)*64 + c*2 + st], v);
  }
}

// ---------------- pass 2 (f32): conv1 -> bn1relu -> conv2 stats (+ z2 store) ----------------
// R23: conv2 via R20 idiom — wave wv owns oc [wv*16,wv*16+16) (SGPR s_load_dwordx16),
// lane: col=t&15, rq=(t>>4)&3 -> output rows 4rq..4rq+3. Per-element FMA order
// (ic outer, j inner) identical to old k_p2 -> z2 bit-identical.
__global__ __launch_bounds__(256) void k_p2(const float* __restrict__ x, const float* __restrict__ wf,
                                            const double* __restrict__ aff1, double* __restrict__ acc2,
                                            float* __restrict__ z2, int nS){
  __shared__ float xp[324];
  __shared__ float h1f[32*324];
  int p=blockIdx.x, t=threadIdx.x;
  for(int i=t;i<324;i+=256) xp[i]=0.f;
  for(int i=t;i<32*324;i+=256) h1f[i]=0.f;
  __syncthreads();
  int py=t>>4, px=t&15;
  xp[(py+1)*18 + px + 1] = x[(size_t)p*256+t];
  __syncthreads();
  {
    float nb[9];
    #pragma unroll
    for(int j=0;j<9;j++) nb[j] = xp[(py+j/3)*18 + px + (j%3)];
    for(int c=0;c<32;c++){
      float a = wf[WS_B1+c];
      #pragma unroll
      for(int j=0;j<9;j++) a = fmaf(nb[j], wf[WS_W1+c*9+j], a);
      h1f[c*324 + (py+1)*18 + (px+1)] = fmaxf(fmaf((float)aff1[2*c], a, (float)aff1[2*c+1]), 0.f);
    }
  }
  __syncthreads();
  int col=t&15, rq=(t>>4)&3;
  int wv = __builtin_amdgcn_readfirstlane(t>>6);   // wave-uniform wave id, oc slice
  float acc[16][4];
  #pragma unroll
  for(int o=0;o<16;o++){
    float bv = wf[WS_B2 + wv*16 + o];
    #pragma unroll
    for(int r=0;r<4;r++) acc[o][r]=bv;
  }
  const f32x16* W2v = reinterpret_cast<const f32x16*>(wf + W2T_F + wv*16); // vec stride: ic=36, j=4
  #pragma unroll 1
  for(int ic=0; ic<32; ++ic){
    float a[6][3];                 // h1f rows 4rq..4rq+5, cols col..col+2
    #pragma unroll
    for(int lr=0; lr<6; ++lr){
      #pragma unroll
      for(int dx=0; dx<3; ++dx) a[lr][dx] = h1f[ic*324 + (4*rq+lr)*18 + col + dx];
    }
    #pragma unroll
    for(int j=0;j<9;j++){
      f32x16 w = W2v[(ic*9 + j)*4];   // uniform -> s_load_dwordx16
      int dy=j/3, dx=j%3;
      #pragma unroll
      for(int o=0;o<16;o++){
        #pragma unroll
        for(int r=0;r<4;r++) acc[o][r] = fmaf(a[r+dy][dx], w[o], acc[o][r]);
      }
    }
  }
  bool wr = (p < nS);
  #pragma unroll
  for(int o=0;o<16;o++){
    int c = wv*16+o;
    if(wr){
      #pragma unroll
      for(int r=0;r<4;r++) z2[((size_t)p*64+c)*256 + (4*rq+r)*16 + col] = acc[o][r];
    }
    double s=0.0, q=0.0;
    #pragma unroll
    for(int r=0;r<4;r++){ double v=(double)acc[o][r]; s+=v; q+=v*v; }
    #pragma unroll
    for(int off=32;off;off>>=1){ s += __shfl_down(s,off); q += __shfl_down(q,off); }
    if((t&63)==0){
      atomicAdd(&acc2[(p&63)*128 + c*2 + 0], s);
      atomicAdd(&acc2[(p&63)*128 + c*2 + 1], q);
    }
  }
}

// ========= STAGED conv3 stats (f32): 512 thr, SMEM weights, 2 rows/lane (R20) =========
// lane map: col = t&15, q = (t>>4)&3 (rows 2q,2q+1), wave wv = t>>6 owns oc [wv*16,wv*16+16)
__global__ __launch_bounds__(512) void k_cs(const float* __restrict__ wf, const double* __restrict__ aff2,
                                            double* __restrict__ acc3, const float* __restrict__ z2){
  __shared__ float h2S[32*200];   // [32 ch][10 rows][20-col stride], 25600 B; stride 20 -> 2-way banks
  int bid=blockIdx.x, t=threadIdx.x;
  int p = bid>>1, r0 = (bid&1)*8;
  for(int i=t;i<6400;i+=512) h2S[i]=0.f;   // halo/pad stays 0 across both halves
  int col=t&15, q=(t>>4)&3;
  int wv = __builtin_amdgcn_readfirstlane(t>>6);   // provably wave-uniform wave id
  float acc[16][2];               // [oc within wave][row]
  #pragma unroll
  for(int o=0;o<16;o++){
    float bv = wf[WS_B3 + wv*16 + o];
    acc[o][0]=bv; acc[o][1]=bv;
  }
  const f32x16* wW = reinterpret_cast<const f32x16*>(wf + WS_W3 + wv*16); // elem stride: ic=72, j=8
  #pragma unroll 1
  for(int half=0; half<2; ++half){
    __syncthreads();              // zero done (h0) / previous half consumed (h1)
    for(int i=t;i<5120;i+=512){   // 32 ch x 10 rows x 16 cols
      int ch2 = i/160, rem = i - ch2*160;
      int row = rem>>4, c2 = rem&15;
      int gr = r0 - 1 + row;
      if(gr>=0 && gr<16){
        int ch = half*32 + ch2;
        float zv = z2[((size_t)p*64+ch)*256 + gr*16 + c2];
        h2S[ch2*200 + row*20 + c2+1] = fmaxf(fmaf((float)aff2[2*ch], zv, (float)aff2[2*ch+1]), 0.f);
      }
    }
    __syncthreads();
    #pragma unroll 1
    for(int ic2=0; ic2<32; ++ic2){
      int ic = half*32 + ic2;
      float a[4][3];              // strip rows 2q..2q+3, cols col..col+2
      #pragma unroll
      for(int lr=0; lr<4; ++lr){
        #pragma unroll
        for(int dx=0; dx<3; ++dx) a[lr][dx] = h2S[ic2*200 + (2*q+lr)*20 + col + dx];
      }
      #pragma unroll
      for(int j=0;j<9;j++){
        f32x16 w = wW[ic*72 + j*8];   // uniform -> s_load_dwordx16; w[o] = SGPR FMA operand
        int dy=j/3, dx=j%3;
        #pragma unroll
        for(int o=0;o<16;o++){
          acc[o][0] = fmaf(a[dy  ][dx], w[o], acc[o][0]);
          acc[o][1] = fmaf(a[dy+1][dx], w[o], acc[o][1]);
        }
      }
    }
  }
  #pragma unroll
  for(int o=0;o<16;o++){
    double s  = (double)acc[o][0] + (double)acc[o][1];
    double q2 = (double)acc[o][0]*(double)acc[o][0] + (double)acc[o][1]*(double)acc[o][1];
    #pragma unroll
    for(int off=32;off;off>>=1){ s += __shfl_down(s,off); q2 += __shfl_down(q2,off); }
    if((t&63)==0){
      int c = wv*16+o;
      atomicAdd(&acc3[(bid&63)*256 + c*2 + 0], s);
      atomicAdd(&acc3[(bid&63)*256 + c*2 + 1], q2);
    }
  }
}

// ========= STAGED conv3 feat (f32 conv, f64 accumulate): same structure (R20) =========
__global__ __launch_bounds__(512) void k_cf(const float* __restrict__ wf, const double* __restrict__ aff2,
                                            const double* __restrict__ aff3, double* __restrict__ feat,
                                            const float* __restrict__ z2){
  __shared__ float h2S[32*200];
  int bid=blockIdx.x, t=threadIdx.x;
  int p = bid>>1, r0 = (bid&1)*8;
  for(int i=t;i<6400;i+=512) h2S[i]=0.f;
  int col=t&15, q=(t>>4)&3;
  int wv = __builtin_amdgcn_readfirstlane(t>>6);
  float acc[16][2];
  #pragma unroll
  for(int o=0;o<16;o++){
    float bv = wf[WS_B3 + wv*16 + o];
    acc[o][0]=bv; acc[o][1]=bv;
  }
  const f32x16* wW = reinterpret_cast<const f32x16*>(wf + WS_W3 + wv*16);
  #pragma unroll 1
  for(int half=0; half<2; ++half){
    __syncthreads();
    for(int i=t;i<5120;i+=512){
      int ch2 = i/160, rem = i - ch2*160;
      int row = rem>>4, c2 = rem&15;
      int gr = r0 - 1 + row;
      if(gr>=0 && gr<16){
        int ch = half*32 + ch2;
        float zv = z2[((size_t)p*64+ch)*256 + gr*16 + c2];
        h2S[ch2*200 + row*20 + c2+1] = fmaxf(fmaf((float)aff2[2*ch], zv, (float)aff2[2*ch+1]), 0.f);
      }
    }
    __syncthreads();
    #pragma unroll 1
    for(int ic2=0; ic2<32; ++ic2){
      int ic = half*32 + ic2;
      float a[4][3];
      #pragma unroll
      for(int lr=0; lr<4; ++lr){
        #pragma unroll
        for(int dx=0; dx<3; ++dx) a[lr][dx] = h2S[ic2*200 + (2*q+lr)*20 + col + dx];
      }
      #pragma unroll
      for(int j=0;j<9;j++){
        f32x16 w = wW[ic*72 + j*8];
        int dy=j/3, dx=j%3;
        #pragma unroll
        for(int o=0;o<16;o++){
          acc[o][0] = fmaf(a[dy  ][dx], w[o], acc[o][0]);
          acc[o][1] = fmaf(a[dy+1][dx], w[o], acc[o][1]);
        }
      }
    }
  }
  #pragma unroll
  for(int o=0;o<16;o++){
    int c = wv*16+o;
    float sc=(float)aff3[2*c], sh=(float)aff3[2*c+1];
    double sv = (double)fmaxf(fmaf(sc, acc[o][0], sh), 0.f)
              + (double)fmaxf(fmaf(sc, acc[o][1], sh), 0.f);
    #pragma unroll
    for(int off=32;off;off>>=1) sv += __shfl_down(sv,off);
    if((t&63)==0) atomicAdd(&feat[(size_t)p*128 + c], sv);
  }
}

// ========= FALLBACK recompute conv3 stats (f32), patches p0.. (dead at current ws_size) =========
__global__ __launch_bounds__(256) void k_stat3(const float* __restrict__ x, const float* __restrict__ wf,
                                               const double* __restrict__ aff1, const double* __restrict__ aff2,
                                               double* __restrict__ acc3, int p0){
  __shared__ float xp[324];
  __shared__ float h1S[32*144];
  __shared__ float h2S[64*108];
  int bid=blockIdx.x, t=threadIdx.x;
  int p = p0 + (bid>>2), r0 = (bid&3)*4;
  for(int i=t;i<64*108;i+=256) h2S[i]=0.f;
  for(int i=t;i<324;i+=256) xp[i]=0.f;
  for(int i=t;i<32*144;i+=256) h1S[i]=0.f;
  __syncthreads();
  { int py=t>>4, px=t&15; xp[(py+1)*18 + px + 1] = x[(size_t)p*256+t]; }
  __syncthreads();
  {
    int rr=t>>5, cw=t&31, col=cw&15, half=cw>>4;
    int p1 = r0-1+rr;
    if(p1>=1 && p1<=16){
      float nb[9];
      #pragma unroll
      for(int j=0;j<9;j++) nb[j] = xp[(p1-1+j/3)*18 + col + (j%3)];
      for(int k=0;k<16;k++){
        int c = half*16+k;
        float a = wf[WS_B1+c];
        #pragma unroll
        for(int j=0;j<9;j++) a = fmaf(nb[j], wf[WS_W1+c*9+j], a);
        h1S[c*144 + rr*18 + col+1] = fmaxf((float)aff1[2*c]*a + (float)aff1[2*c+1], 0.f);
      }
    }
  }
  __syncthreads();
  {
    int col=t&15, g=t>>4;
    float a24[4][6];
    #pragma unroll
    for(int o=0;o<4;o++){
      float bv = wf[WS_B2+g*4+o];
      #pragma unroll
      for(int b2=0;b2<6;b2++) a24[o][b2] = bv;
    }
    #pragma unroll 1
    for(int ic=0;ic<32;ic++){
      const float* wrow = wf + WS_W2 + (g*4*32 + ic)*9;
      #pragma unroll
      for(int j=0;j<9;j++){
        float w4[4];
        #pragma unroll
        for(int o=0;o<4;o++) w4[o] = wrow[o*288 + j];
        int dy=j/3, dx=j%3;
        #pragma unroll
        for(int b2=0;b2<6;b2++){
          float m = h1S[ic*144 + (b2+dy)*18 + col + dx];
          #pragma unroll
          for(int o=0;o<4;o++) a24[o][b2] = fmaf(m, w4[o], a24[o][b2]);
        }
      }
    }
    #pragma unroll
    for(int b2=0;b2<6;b2++){
      int p2 = r0+b2;
      if(p2>=1 && p2<=16){
        #pragma unroll
        for(int o=0;o<4;o++){
          int c=g*4+o;
          h2S[c*108 + b2*18 + col+1] = fmaxf((float)aff2[2*c]*a24[o][b2] + (float)aff2[2*c+1], 0.f);
        }
      }
    }
  }
  __syncthreads();
  {
    int col = t & 15, og = t >> 4;
    float acc[8][4];
    #pragma unroll
    for(int o=0;o<8;o++){
      float bv = wf[WS_B3 + og*8 + o];
      #pragma unroll
      for(int r=0;r<4;r++) acc[o][r] = bv;
    }
    #pragma unroll 1
    for(int ic=0; ic<64; ++ic){
      float a[6][3];
      #pragma unroll
      for(int rr=0; rr<6; ++rr){
        #pragma unroll
        for(int dx=0; dx<3; ++dx) a[rr][dx] = h2S[ic*108 + rr*18 + col + dx];
      }
      const float* wrow = wf + WS_W3 + ic*1152;   // j-major layout (R18)
      #pragma unroll
      for(int o=0;o<8;o++){
        #pragma unroll
        for(int j=0;j<9;j++){
          float w = wrow[j*128 + og*8 + o];
          #pragma unroll
          for(int r=0;r<4;r++) acc[o][r] = fmaf(a[r + j/3][j%3], w, acc[o][r]);
        }
      }
    }
    #pragma unroll
    for(int o=0;o<8;o++){
      double s=0.0, q=0.0;
      #pragma unroll
      for(int r=0;r<4;r++){ double v=(double)acc[o][r]; s+=v; q+=v*v; }
      #pragma unroll
      for(int off=8; off; off>>=1){ s += __shfl_down(s, off, 16); q += __shfl_down(q, off, 16); }
      if(col==0){
        int c = og*8+o;
        atomicAdd(&acc3[(bid&63)*256 + c*2 + 0], s);
        atomicAdd(&acc3[(bid&63)*256 + c*2 + 1], q);
      }
    }
  }
}

// ========= FALLBACK recompute conv3 feat (f32, f64 accumulate), patches p0.. (dead) =========
__global__ __launch_bounds__(256) void k_p34(const float* __restrict__ x, const float* __restrict__ wf,
                                             const double* __restrict__ aff1, const double* __restrict__ aff2,
                                             const double* __restrict__ aff3, double* __restrict__ outp,
                                             int p0){
  __shared__ float xp[324];
  __shared__ float h1S[32*144];
  __shared__ float h2S[64*108];
  int bid=blockIdx.x, t=threadIdx.x;
  int p = p0 + (bid>>2), r0 = (bid&3)*4;
  for(int i=t;i<64*108;i+=256) h2S[i]=0.f;
  for(int i=t;i<324;i+=256) xp[i]=0.f;
  for(int i=t;i<32*144;i+=256) h1S[i]=0.f;
  __syncthreads();
  { int py=t>>4, px=t&15; xp[(py+1)*18 + px + 1] = x[(size_t)p*256+t]; }
  __syncthreads();
  {
    int rr=t>>5, cw=t&31, col=cw&15, half=cw>>4;
    int p1 = r0-1+rr;
    if(p1>=1 && p1<=16){
      float nb[9];
      #pragma unroll
      for(int j=0;j<9;j++) nb[j] = xp[(p1-1+j/3)*18 + col + (j%3)];
      for(int k=0;k<16;k++){
        int c = half*16+k;
        float a = wf[WS_B1+c];
        #pragma unroll
        for(int j=0;j<9;j++) a = fmaf(nb[j], wf[WS_W1+c*9+j], a);
        h1S[c*144 + rr*18 + col+1] = fmaxf((float)aff1[2*c]*a + (float)aff1[2*c+1], 0.f);
      }
    }
  }
  __syncthreads();
  {
    int col=t&15, g=t>>4;
    float a24[4][6];
    #pragma unroll
    for(int o=0;o<4;o++){
      float bv = wf[WS_B2+g*4+o];
      #pragma unroll
      for(int b2=0;b2<6;b2++) a24[o][b2] = bv;
    }
    #pragma unroll 1
    for(int ic=0;ic<32;ic++){
      const float* wrow = wf + WS_W2 + (g*4*32 + ic)*9;
      #pragma unroll
      for(int j=0;j<9;j++){
        float w4[4];
        #pragma unroll
        for(int o=0;o<4;o++) w4[o] = wrow[o*288 + j];
        int dy=j/3, dx=j%3;
        #pragma unroll
        for(int b2=0;b2<6;b2++){
          float m = h1S[ic*144 + (b2+dy)*18 + col + dx];
          #pragma unroll
          for(int o=0;o<4;o++) a24[o][b2] = fmaf(m, w4[o], a24[o][b2]);
        }
      }
    }
    #pragma unroll
    for(int b2=0;b2<6;b2++){
      int p2 = r0+b2;
      if(p2>=1 && p2<=16){
        #pragma unroll
        for(int o=0;o<4;o++){
          int c=g*4+o;
          h2S[c*108 + b2*18 + col+1] = fmaxf((float)aff2[2*c]*a24[o][b2] + (float)aff2[2*c+1], 0.f);
        }
      }
    }
  }
  __syncthreads();
  {
    int col = t & 15, og = t >> 4;
    float acc[8][4];
    #pragma unroll
    for(int o=0;o<8;o++){
      float bv = wf[WS_B3 + og*8 + o];
      #pragma unroll
      for(int r=0;r<4;r++) acc[o][r] = bv;
    }
    #pragma unroll 1
    for(int ic=0; ic<64; ++ic){
      float a[6][3];
      #pragma unroll
      for(int rr=0; rr<6; ++rr){
        #pragma unroll
        for(int dx=0; dx<3; ++dx) a[rr][dx] = h2S[ic*108 + rr*18 + col + dx];
      }
      const float* wrow = wf + WS_W3 + ic*1152;   // j-major layout (R18)
      #pragma unroll
      for(int o=0;o<8;o++){
        #pragma unroll
        for(int j=0;j<9;j++){
          float w = wrow[j*128 + og*8 + o];
          #pragma unroll
          for(int r=0;r<4;r++) acc[o][r] = fmaf(a[r + j/3][j%3], w, acc[o][r]);
        }
      }
    }
    #pragma unroll
    for(int o=0;o<8;o++){
      int c = og*8+o;
      float sc=(float)aff3[2*c], sh=(float)aff3[2*c+1];
      double s = 0.0;
      #pragma unroll
      for(int r=0;r<4;r++) s += (double)fmaxf(fmaf(sc, acc[o][r], sh), 0.f);
      #pragma unroll
      for(int off=8; off; off>>=1) s += __shfl_down(s, off, 16);
      if(col==0) atomicAdd(&outp[(size_t)p*128 + c], s);
    }
  }
}

// ---------------- LN + relu on [4][512] f64 LDS buffer ----------------
__device__ __forceinline__ void ln_relu4(double* buf, const float* __restrict__ g, const float* __restrict__ b,
                                         double* lnm, double* lnr, int t){
  int r=t>>6, j=t&63;
  double s=0.0, q=0.0;
  for(int k=j;k<512;k+=64){ double v=buf[r*512+k]; s+=v; q+=v*v; }
  #pragma unroll
  for(int off=32;off;off>>=1){ s+=__shfl_down(s,off); q+=__shfl_down(q,off); }
  if(j==0){
    double m = s*(1.0/512.0);
    double v = q*(1.0/512.0) - m*m;
    lnm[r]=m; lnr[r]=1.0/sqrt(v + 1e-5);
  }
  __syncthreads();
  for(int i=t;i<2048;i+=256){
    int r2=i>>9, k=i&511;
    double v=(buf[i]-lnm[r2])*lnr[r2]*(double)g[k]+(double)b[k];
    buf[i]=fmax(v,0.0);
  }
  __syncthreads();
}

// ---------------- MLP head (f64): feat -> assignment f32 (4 rows/block; R12 version) ----------------
__global__ __launch_bounds__(256) void k_mlp(const float* __restrict__ wf, const double* __restrict__ feat,
                                             float* __restrict__ assign_out){
  int r0 = blockIdx.x*4, t = threadIdx.x;
  __shared__ double f0[4*128];
  __shared__ double f1[4*256];
  __shared__ double f2[4*512];
  __shared__ double f3[4*512];
  __shared__ double lnm[4], lnr[4];
  __shared__ double lg[4][8];

  for(int i=t;i<512;i+=256) f0[i] = feat[(size_t)r0*128 + i] * (1.0/256.0);
  __syncthreads();
  {
    double acc[4];
    double bv = (double)wf[WS_FCB + t];
    #pragma unroll
    for(int r=0;r<4;r++) acc[r]=bv;
    for(int k=0;k<128;k++){
      double wv = (double)wf[WS_FCW + t*128 + k];
      #pragma unroll
      for(int r=0;r<4;r++) acc[r]=fma(wv, f0[r*128+k], acc[r]);
    }
    #pragma unroll
    for(int r=0;r<4;r++) f1[r*256+t]=acc[r];
  }
  __syncthreads();
  for(int half=0;half<2;half++){
    int i=t+(half<<8);
    double acc[4];
    double bv=(double)wf[WS_G1B+i];
    #pragma unroll
    for(int r=0;r<4;r++) acc[r]=bv;
    for(int k=0;k<256;k++){
      double wv=(double)wf[WS_G1W + i*256 + k];
      #pragma unroll
      for(int r=0;r<4;r++) acc[r]=fma(wv, f1[r*256+k], acc[r]);
    }
    #pragma unroll
    for(int r=0;r<4;r++) f2[r*512+i]=acc[r];
  }
  __syncthreads();
  ln_relu4(f2, wf+WS_L1G, wf+WS_L1B, lnm, lnr, t);
  for(int half=0;half<2;half++){
    int i=t+(half<<8);
    double acc[4];
    double bv=(double)wf[WS_G2B+i];
    #pragma unroll
    for(int r=0;r<4;r++) acc[r]=bv;
    for(int k=0;k<512;k++){
      double wv=(double)wf[WS_G2W + i*512 + k];
      #pragma unroll
      for(int r=0;r<4;r++) acc[r]=fma(wv, f2[r*512+k], acc[r]);
    }
    #pragma unroll
    for(int r=0;r<4;r++) f3[r*512+i]=acc[r];
  }
  __syncthreads();
  ln_relu4(f3, wf+WS_L2G, wf+WS_L2B, lnm, lnr, t);
  {
    int r=t>>6, j=t&63;
    double pl[8];
    #pragma unroll
    for(int g=0;g<8;g++){
      double s=0.0;
      for(int k=j;k<512;k+=64) s = fma(f3[r*512+k], (double)wf[WS_G3W + g*512 + k], s);
      pl[g]=s;
    }
    #pragma unroll
    for(int off=32;off;off>>=1){
      #pragma unroll
      for(int g=0;g<8;g++) pl[g] += __shfl_down(pl[g], off);
    }
    if(j==0){
      #pragma unroll
      for(int g=0;g<8;g++) lg[r][g] = (pl[g] + (double)wf[WS_G3B+g]) * 2.0; // /TEMP
    }
  }
  __syncthreads();
  if(t<4){
    double m=-1e300;
    #pragma unroll
    for(int g=0;g<8;g++) m = fmax(m, lg[t][g]);
    double e[8], s=0.0;
    #pragma unroll
    for(int g=0;g<8;g++){ e[g]=exp(lg[t][g]-m); s+=e[g]; }
    double inv = 1.0/s;
    int row = r0 + t;
    #pragma unroll
    for(int g=0;g<8;g++) assign_out[row*8+g] = (float)(e[g]*inv);
  }
}

// ---------------- top-32 per (b,g) + gather*scale ----------------
__global__ __launch_bounds__(256) void k_topk(const float* __restrict__ assign, const float* __restrict__ x,
                                              float* __restrict__ out){
  int b = blockIdx.x >> 3, g = blockIdx.x & 7, t = threadIdx.x;
  __shared__ float v[256];
  __shared__ int   id[256];
  v[t] = assign[(b*256+t)*8 + g];
  id[t] = t;
  __syncthreads();
  for(int k=2;k<=256;k<<=1){
    for(int j=k>>1;j>0;j>>=1){
      int ixj = t ^ j;
      if(ixj > t){
        float va=v[t], vb=v[ixj];
        int ia=id[t], ib=id[ixj];
        bool aBefore = (va > vb) || (va == vb && ia < ib);
        bool up = ((t & k) == 0);
        if(up != aBefore){ v[t]=vb; v[ixj]=va; id[t]=ib; id[ixj]=ia; }
      }
      __syncthreads();
    }
  }
  __shared__ float tv[32];
  __shared__ int   ti[32];
  if(t<32){ tv[t]=v[t]; ti[t]=id[t]; }
  __syncthreads();
  const float* xb = x + (size_t)b*65536;
  float* ob = out + (size_t)(b*8+g)*8192;
  for(int i=t;i<8192;i+=256){
    int k=i>>8, pix=i&255;
    ob[i] = tv[k] * xb[ti[k]*256 + pix];
  }
}

// ---------------- launcher ----------------
extern "C" void kernel_launch(void* const* d_in, const int* in_sizes, int n_in,
                              void* d_out, int out_size, void* d_ws, size_t ws_size,
                              hipStream_t stream){
  const float* x = (const float*)d_in[0];
  float*  ws  = (float*)d_ws;
  double* dws = (double*)d_ws;
  float* out = (float*)d_out;
  float* assign_out = out + 1048576;
  float* z2 = (float*)((char*)d_ws + Z2_OFF_B);

  int nS = 0;
  if(ws_size > Z2_OFF_B + 65536){
    unsigned long long avail = (unsigned long long)ws_size - Z2_OFF_B;
    unsigned long long n = avail / 65536ull;
    nS = (n > 4096ull) ? 4096 : (int)n;
  }
  int nR = 4096 - nS;

  const float* g1=(const float*)d_in[3];  const float* b1=(const float*)d_in[4];
  const float* g2=(const float*)d_in[7];  const float* b2=(const float*)d_in[8];
  const float* g3=(const float*)d_in[11]; const float* b3=(const float*)d_in[12];

  WP wp;
  const int map[18] = {1,2,5,6,9,10,13,14,15,16,17,18,19,20,21,22,23,24};
  for(int i=0;i<18;i++) wp.p[i] = (const float*)d_in[map[i]];

  k_zero <<<2162, 256, 0, stream>>>(dws + D_ACC1);
  k_cvt  <<<dim3(1024,19), 256, 0, stream>>>(wp, ws);
  k_p1   <<<4096, 256, 0, stream>>>(x, ws, dws+D_ACC1);
  k_fin  <<<32, 64, 0, stream>>>(dws+D_ACC1, 32, g1, b1, dws+D_AFF1);
  k_p2   <<<4096, 256, 0, stream>>>(x, ws, dws+D_AFF1, dws+D_ACC2, z2, nS);
  k_fin  <<<64, 64, 0, stream>>>(dws+D_ACC2, 64, g2, b2, dws+D_AFF2);
  if(nS > 0) k_cs   <<<2*nS, 512, 0, stream>>>(ws, dws+D_AFF2, dws+D_ACC3, z2);
  if(nR > 0) k_stat3<<<4*nR, 256, 0, stream>>>(x, ws, dws+D_AFF1, dws+D_AFF2, dws+D_ACC3, nS);
  k_fin  <<<128, 64, 0, stream>>>(dws+D_ACC3, 128, g3, b3, dws+D_AFF3);
  if(nS > 0) k_cf  <<<2*nS, 512, 0, stream>>>(ws, dws+D_AFF2, dws+D_AFF3, dws+D_FEAT, z2);
  if(nR > 0) k_p34 <<<4*nR, 256, 0, stream>>>(x, ws, dws+D_AFF1, dws+D_AFF2, dws+D_AFF3, dws+D_FEAT, nS);
  k_mlp  <<<1024, 256, 0, stream>>>(ws, dws+D_FEAT, assign_out);
  k_topk <<<128, 256, 0, stream>>>(assign_out, x, out);
}

// Round 11
// 3943.826 us; speedup vs baseline: 1.4041x; 1.0160x over previous
//
#include <hip/hip_runtime.h>

// Inputs f32, outputs f32. Precision map (all hardware-validated):
//   - BN stats passes (k_p1, conv2/conv3 stats): f32 conv + f64 accumulate —
//     1M-pixel averages wash out rounding (R12/R14, absmax at floor).
//   - Value chain conv: f32; BN affine / feat accumulate / MLP / softmax: f64
//     (R4: cheap f32 here caused top-k rank swaps).
// Conv weights f32 (f64 weights thrash L1: R7/R9). z2 staged f32 (R11).
// R20 (WIN): wave-uniform 16-oc slice -> s_load_dwordx16 weights as SGPR FMA
// operands; conv3 at ~91% of measured 103-TF practical FMA ceiling.
// R21 flat; R22 Winograd regressed (SGPR prefetch budget: 4 concurrent
// 16-SGPR groups expose s_load latency, duty 88->51). R23/24: k_p2 ported
// to R20 idiom (W2T j-major SGPR weights); total 4007us (best).
// R25 REFUTED: f16 z3 staging to kill the 2nd conv3 pass -> absmax 0.78 =
// top-k RANK SWAPS. Mechanism: 0.01-scale MLP weights -> logits near 0 ->
// assignment clusters at 1/8 -> top-32 gaps << 1e-4; the ~3e-5 feat
// perturbation from f16 flips ranks. Extends R4: NO reduced-precision z3
// staging is viable. Stats pass irreducible (variance = nonlinear).
// R26: revert to R24 verbatim. Conv3 two-pass structure is forced and runs
// at 87-91% of the measured practical ceiling -> at roofline if reproduced.

typedef float f32x16 __attribute__((ext_vector_type(16)));

// ---- f32 weight block (float offsets into ws) ----
#define WS_W1   0
#define WS_B1   288
#define WS_W2   320
#define WS_B2   18752
#define WS_W3   18816
#define WS_B3   92544
#define WS_FCW  92672
#define WS_FCB  125440
#define WS_G1W  125696
#define WS_G1B  256768
#define WS_L1G  257280
#define WS_L1B  257792
#define WS_G2W  258304
#define WS_G2B  520448
#define WS_L2G  520960
#define WS_L2B  521472
#define WS_G3W  521984
#define WS_G3B  526080
// ---- f64 region (double offsets into ws) ----
#define D_ACC1  263044
#define D_ACC2  (D_ACC1 + 4096)
#define D_ACC3  (D_ACC2 + 8192)
#define D_FEAT  (D_ACC3 + 16384)
#define D_AFF1  (D_FEAT + 524288)
#define D_AFF2  (D_AFF1 + 64)
#define D_AFF3  (D_AFF2 + 128)
#define D_ZN    553408        // doubles zeroed from D_ACC1; region ends at byte 6,531,616
// ---- W2T: j-major conv2 weights [ic][j][oc], after f64 region ----
#define W2T_F   1632912       // byte 6,531,648; 18432 floats
// ---- z2 staging: first 512-aligned byte AFTER W2T ----
#define Z2_OFF_B 6605824ull

// W3 j-major layout: offset = ic*1152 + j*128 + oc (max 73727).
// Wave wv owns oc [wv*16, wv*16+16): one 64-B-aligned float16 per (ic,j)
// at WS_W3 + ic*1152 + j*128 + wv*16 — wave-uniform => s_load.

// ---------------- zero f64 accumulators ----------------
__global__ __launch_bounds__(256) void k_zero(double* __restrict__ dst){
  int i = blockIdx.x*256 + threadIdx.x;
  if(i < D_ZN) dst[i] = 0.0;
}

// ---------------- weight gather-copy (f32; W3 j-major, W2T j-major) ----------------
struct WP { const float* p[18]; };

__global__ __launch_bounds__(256) void k_cvt(WP wp, float* __restrict__ dst){
  int s = blockIdx.y;
  int i = blockIdx.x*256 + threadIdx.x;
  if(s == 18){
    // conv2 weights (64,32,3,3): i = (oc*32+ic)*9 + j -> j-major [ic][j][oc]
    if(i < 18432){
      int oc = i / 288;
      int rem = i - oc*288;
      int ic = rem / 9;
      int j  = rem - ic*9;
      dst[W2T_F + ic*576 + j*64 + oc] = wp.p[2][i];
    }
    return;
  }
  const int segn[18] = {288,32,18432,64,73728,128,32768,256,131072,512,512,512,262144,512,512,512,4096,8};
  const int sego[18] = {WS_W1,WS_B1,WS_W2,WS_B2,WS_W3,WS_B3,WS_FCW,WS_FCB,WS_G1W,WS_G1B,
                        WS_L1G,WS_L1B,WS_G2W,WS_G2B,WS_L2G,WS_L2B,WS_G3W,WS_G3B};
  if(i < segn[s]){
    if(s == 4){
      // src (OIHW flat): i = (oc*64 + ic)*9 + j  ->  j-major packed layout
      int oc = i / 576;
      int rem = i - oc*576;
      int ic = rem / 9;
      int j  = rem - ic*9;
      dst[WS_W3 + ic*1152 + j*128 + oc] = wp.p[4][i];
    } else {
      dst[sego[s]+i] = wp.p[s][i];
    }
  }
}

// ---------------- finalize BN stats ----------------
__global__ __launch_bounds__(64) void k_fin(const double* __restrict__ acc, int C,
                                            const float* __restrict__ gam, const float* __restrict__ bet,
                                            double* __restrict__ aff){
  int c = blockIdx.x, t = threadIdx.x;
  double s = acc[t*2*C + c*2];
  double q = acc[t*2*C + c*2 + 1];
  #pragma unroll
  for(int off=32;off;off>>=1){ s += __shfl_down(s,off); q += __shfl_down(q,off); }
  if(t==0){
    double m = s*(1.0/1048576.0);
    double v = q*(1.0/1048576.0) - m*m;
    double sc = (double)gam[c] / sqrt(v + 1e-5);
    aff[2*c]   = sc;
    aff[2*c+1] = (double)bet[c] - m*sc;
  }
}

// ---------------- pass 1: conv1 raw stats (f32 conv, f64 accumulate) ----------------
__global__ __launch_bounds__(256) void k_p1(const float* __restrict__ x, const float* __restrict__ wf,
                                            double* __restrict__ acc1){
  __shared__ float xp[324];
  __shared__ double red[4][32][2];
  int p = blockIdx.x, t = threadIdx.x;
  for(int i=t;i<324;i+=256) xp[i]=0.f;
  __syncthreads();
  int py=t>>4, px=t&15;
  xp[(py+1)*18 + px + 1] = x[(size_t)p*256+t];
  __syncthreads();
  float nb[9];
  #pragma unroll
  for(int j=0;j<9;j++) nb[j] = xp[(py+j/3)*18 + px + (j%3)];
  int wave=t>>6, lane=t&63;
  for(int c=0;c<32;c++){
    float a = wf[WS_B1+c];
    #pragma unroll
    for(int j=0;j<9;j++) a = fmaf(nb[j], wf[WS_W1+c*9+j], a);
    double av=(double)a;
    double s=av, q=av*av;
    #pragma unroll
    for(int off=32;off;off>>=1){ s+=__shfl_down(s,off); q+=__shfl_down(q,off); }
    if(lane==0){ red[wave][c][0]=s; red[wave][c][1]=q; }
  }
  __syncthreads();
  if(t<64){
    int c=t>>1, st=t&1;
    double v = red[0][c][st]+red[1][c][st]+red[2][c][st]+red[3][c][st];
    atomicAdd(&acc1[(p&63)*64 + c*2 + st], v);
  }
}

// ---------------- pass 2 (f32): conv1 -> bn1relu -> conv2 stats (+ z2 store) ----------------
// conv2 via R20 idiom — wave wv owns oc [wv*16,wv*16+16) (SGPR s_load_dwordx16),
// lane: col=t&15, rq=(t>>4)&3 -> output rows 4rq..4rq+3. Per-element FMA order
// (ic outer, j inner) identical to old k_p2 -> z2 bit-identical.
__global__ __launch_bounds__(256) void k_p2(const float* __restrict__ x, const float* __restrict__ wf,
                                            const double* __restrict__ aff1, double* __restrict__ acc2,
                                            float* __restrict__ z2, int nS){
  __shared__ float xp[324];
  __shared__ float h1f[32*324];
  int p=blockIdx.x, t=threadIdx.x;
  for(int i=t;i<324;i+=256) xp[i]=0.f;
  for(int i=t;i<32*324;i+=256) h1f[i]=0.f;
  __syncthreads();
  int py=t>>4, px=t&15;
  xp[(py+1)*18 + px + 1] = x[(size_t)p*256+t];
  __syncthreads();
  {
    float nb[9];
    #pragma unroll
    for(int j=0;j<9;j++) nb[j] = xp[(py+j/3)*18 + px + (j%3)];
    for(int c=0;c<32;c++){
      float a = wf[WS_B1+c];
      #pragma unroll
      for(int j=0;j<9;j++) a = fmaf(nb[j], wf[WS_W1+c*9+j], a);
      h1f[c*324 + (py+1)*18 + (px+1)] = fmaxf(fmaf((float)aff1[2*c], a, (float)aff1[2*c+1]), 0.f);
    }
  }
  __syncthreads();
  int col=t&15, rq=(t>>4)&3;
  int wv = __builtin_amdgcn_readfirstlane(t>>6);   // wave-uniform wave id, oc slice
  float acc[16][4];
  #pragma unroll
  for(int o=0;o<16;o++){
    float bv = wf[WS_B2 + wv*16 + o];
    #pragma unroll
    for(int r=0;r<4;r++) acc[o][r]=bv;
  }
  const f32x16* W2v = reinterpret_cast<const f32x16*>(wf + W2T_F + wv*16); // vec stride: ic=36, j=4
  #pragma unroll 1
  for(int ic=0; ic<32; ++ic){
    float a[6][3];                 // h1f rows 4rq..4rq+5, cols col..col+2
    #pragma unroll
    for(int lr=0; lr<6; ++lr){
      #pragma unroll
      for(int dx=0; dx<3; ++dx) a[lr][dx] = h1f[ic*324 + (4*rq+lr)*18 + col + dx];
    }
    #pragma unroll
    for(int j=0;j<9;j++){
      f32x16 w = W2v[(ic*9 + j)*4];   // uniform -> s_load_dwordx16
      int dy=j/3, dx=j%3;
      #pragma unroll
      for(int o=0;o<16;o++){
        #pragma unroll
        for(int r=0;r<4;r++) acc[o][r] = fmaf(a[r+dy][dx], w[o], acc[o][r]);
      }
    }
  }
  bool wr = (p < nS);
  #pragma unroll
  for(int o=0;o<16;o++){
    int c = wv*16+o;
    if(wr){
      #pragma unroll
      for(int r=0;r<4;r++) z2[((size_t)p*64+c)*256 + (4*rq+r)*16 + col] = acc[o][r];
    }
    double s=0.0, q=0.0;
    #pragma unroll
    for(int r=0;r<4;r++){ double v=(double)acc[o][r]; s+=v; q+=v*v; }
    #pragma unroll
    for(int off=32;off;off>>=1){ s += __shfl_down(s,off); q += __shfl_down(q,off); }
    if((t&63)==0){
      atomicAdd(&acc2[(p&63)*128 + c*2 + 0], s);
      atomicAdd(&acc2[(p&63)*128 + c*2 + 1], q);
    }
  }
}

// ========= STAGED conv3 stats (f32): 512 thr, SMEM weights, 2 rows/lane (R20) =========
// lane map: col = t&15, q = (t>>4)&3 (rows 2q,2q+1), wave wv = t>>6 owns oc [wv*16,wv*16+16)
__global__ __launch_bounds__(512) void k_cs(const float* __restrict__ wf, const double* __restrict__ aff2,
                                            double* __restrict__ acc3, const float* __restrict__ z2){
  __shared__ float h2S[32*200];   // [32 ch][10 rows][20-col stride], 25600 B; stride 20 -> 2-way banks
  int bid=blockIdx.x, t=threadIdx.x;
  int p = bid>>1, r0 = (bid&1)*8;
  for(int i=t;i<6400;i+=512) h2S[i]=0.f;   // halo/pad stays 0 across both halves
  int col=t&15, q=(t>>4)&3;
  int wv = __builtin_amdgcn_readfirstlane(t>>6);   // provably wave-uniform wave id
  float acc[16][2];               // [oc within wave][row]
  #pragma unroll
  for(int o=0;o<16;o++){
    float bv = wf[WS_B3 + wv*16 + o];
    acc[o][0]=bv; acc[o][1]=bv;
  }
  const f32x16* wW = reinterpret_cast<const f32x16*>(wf + WS_W3 + wv*16); // elem stride: ic=72, j=8
  #pragma unroll 1
  for(int half=0; half<2; ++half){
    __syncthreads();              // zero done (h0) / previous half consumed (h1)
    for(int i=t;i<5120;i+=512){   // 32 ch x 10 rows x 16 cols
      int ch2 = i/160, rem = i - ch2*160;
      int row = rem>>4, c2 = rem&15;
      int gr = r0 - 1 + row;
      if(gr>=0 && gr<16){
        int ch = half*32 + ch2;
        float zv = z2[((size_t)p*64+ch)*256 + gr*16 + c2];
        h2S[ch2*200 + row*20 + c2+1] = fmaxf(fmaf((float)aff2[2*ch], zv, (float)aff2[2*ch+1]), 0.f);
      }
    }
    __syncthreads();
    #pragma unroll 1
    for(int ic2=0; ic2<32; ++ic2){
      int ic = half*32 + ic2;
      float a[4][3];              // strip rows 2q..2q+3, cols col..col+2
      #pragma unroll
      for(int lr=0; lr<4; ++lr){
        #pragma unroll
        for(int dx=0; dx<3; ++dx) a[lr][dx] = h2S[ic2*200 + (2*q+lr)*20 + col + dx];
      }
      #pragma unroll
      for(int j=0;j<9;j++){
        f32x16 w = wW[ic*72 + j*8];   // uniform -> s_load_dwordx16; w[o] = SGPR FMA operand
        int dy=j/3, dx=j%3;
        #pragma unroll
        for(int o=0;o<16;o++){
          acc[o][0] = fmaf(a[dy  ][dx], w[o], acc[o][0]);
          acc[o][1] = fmaf(a[dy+1][dx], w[o], acc[o][1]);
        }
      }
    }
  }
  #pragma unroll
  for(int o=0;o<16;o++){
    double s  = (double)acc[o][0] + (double)acc[o][1];
    double q2 = (double)acc[o][0]*(double)acc[o][0] + (double)acc[o][1]*(double)acc[o][1];
    #pragma unroll
    for(int off=32;off;off>>=1){ s += __shfl_down(s,off); q2 += __shfl_down(q2,off); }
    if((t&63)==0){
      int c = wv*16+o;
      atomicAdd(&acc3[(bid&63)*256 + c*2 + 0], s);
      atomicAdd(&acc3[(bid&63)*256 + c*2 + 1], q2);
    }
  }
}

// ========= STAGED conv3 feat (f32 conv, f64 accumulate): same structure (R20) =========
__global__ __launch_bounds__(512) void k_cf(const float* __restrict__ wf, const double* __restrict__ aff2,
                                            const double* __restrict__ aff3, double* __restrict__ feat,
                                            const float* __restrict__ z2){
  __shared__ float h2S[32*200];
  int bid=blockIdx.x, t=threadIdx.x;
  int p = bid>>1, r0 = (bid&1)*8;
  for(int i=t;i<6400;i+=512) h2S[i]=0.f;
  int col=t&15, q=(t>>4)&3;
  int wv = __builtin_amdgcn_readfirstlane(t>>6);
  float acc[16][2];
  #pragma unroll
  for(int o=0;o<16;o++){
    float bv = wf[WS_B3 + wv*16 + o];
    acc[o][0]=bv; acc[o][1]=bv;
  }
  const f32x16* wW = reinterpret_cast<const f32x16*>(wf + WS_W3 + wv*16);
  #pragma unroll 1
  for(int half=0; half<2; ++half){
    __syncthreads();
    for(int i=t;i<5120;i+=512){
      int ch2 = i/160, rem = i - ch2*160;
      int row = rem>>4, c2 = rem&15;
      int gr = r0 - 1 + row;
      if(gr>=0 && gr<16){
        int ch = half*32 + ch2;
        float zv = z2[((size_t)p*64+ch)*256 + gr*16 + c2];
        h2S[ch2*200 + row*20 + c2+1] = fmaxf(fmaf((float)aff2[2*ch], zv, (float)aff2[2*ch+1]), 0.f);
      }
    }
    __syncthreads();
    #pragma unroll 1
    for(int ic2=0; ic2<32; ++ic2){
      int ic = half*32 + ic2;
      float a[4][3];
      #pragma unroll
      for(int lr=0; lr<4; ++lr){
        #pragma unroll
        for(int dx=0; dx<3; ++dx) a[lr][dx] = h2S[ic2*200 + (2*q+lr)*20 + col + dx];
      }
      #pragma unroll
      for(int j=0;j<9;j++){
        f32x16 w = wW[ic*72 + j*8];
        int dy=j/3, dx=j%3;
        #pragma unroll
        for(int o=0;o<16;o++){
          acc[o][0] = fmaf(a[dy  ][dx], w[o], acc[o][0]);
          acc[o][1] = fmaf(a[dy+1][dx], w[o], acc[o][1]);
        }
      }
    }
  }
  #pragma unroll
  for(int o=0;o<16;o++){
    int c = wv*16+o;
    float sc=(float)aff3[2*c], sh=(float)aff3[2*c+1];
    double sv = (double)fmaxf(fmaf(sc, acc[o][0], sh), 0.f)
              + (double)fmaxf(fmaf(sc, acc[o][1], sh), 0.f);
    #pragma unroll
    for(int off=32;off;off>>=1) sv += __shfl_down(sv,off);
    if((t&63)==0) atomicAdd(&feat[(size_t)p*128 + c], sv);
  }
}

// ========= FALLBACK recompute conv3 stats (f32), patches p0.. (dead at current ws_size) =========
__global__ __launch_bounds__(256) void k_stat3(const float* __restrict__ x, const float* __restrict__ wf,
                                               const double* __restrict__ aff1, const double* __restrict__ aff2,
                                               double* __restrict__ acc3, int p0){
  __shared__ float xp[324];
  __shared__ float h1S[32*144];
  __shared__ float h2S[64*108];
  int bid=blockIdx.x, t=threadIdx.x;
  int p = p0 + (bid>>2), r0 = (bid&3)*4;
  for(int i=t;i<64*108;i+=256) h2S[i]=0.f;
  for(int i=t;i<324;i+=256) xp[i]=0.f;
  for(int i=t;i<32*144;i+=256) h1S[i]=0.f;
  __syncthreads();
  { int py=t>>4, px=t&15; xp[(py+1)*18 + px + 1] = x[(size_t)p*256+t]; }
  __syncthreads();
  {
    int rr=t>>5, cw=t&31, col=cw&15, half=cw>>4;
    int p1 = r0-1+rr;
    if(p1>=1 && p1<=16){
      float nb[9];
      #pragma unroll
      for(int j=0;j<9;j++) nb[j] = xp[(p1-1+j/3)*18 + col + (j%3)];
      for(int k=0;k<16;k++){
        int c = half*16+k;
        float a = wf[WS_B1+c];
        #pragma unroll
        for(int j=0;j<9;j++) a = fmaf(nb[j], wf[WS_W1+c*9+j], a);
        h1S[c*144 + rr*18 + col+1] = fmaxf((float)aff1[2*c]*a + (float)aff1[2*c+1], 0.f);
      }
    }
  }
  __syncthreads();
  {
    int col=t&15, g=t>>4;
    float a24[4][6];
    #pragma unroll
    for(int o=0;o<4;o++){
      float bv = wf[WS_B2+g*4+o];
      #pragma unroll
      for(int b2=0;b2<6;b2++) a24[o][b2] = bv;
    }
    #pragma unroll 1
    for(int ic=0;ic<32;ic++){
      const float* wrow = wf + WS_W2 + (g*4*32 + ic)*9;
      #pragma unroll
      for(int j=0;j<9;j++){
        float w4[4];
        #pragma unroll
        for(int o=0;o<4;o++) w4[o] = wrow[o*288 + j];
        int dy=j/3, dx=j%3;
        #pragma unroll
        for(int b2=0;b2<6;b2++){
          float m = h1S[ic*144 + (b2+dy)*18 + col + dx];
          #pragma unroll
          for(int o=0;o<4;o++) a24[o][b2] = fmaf(m, w4[o], a24[o][b2]);
        }
      }
    }
    #pragma unroll
    for(int b2=0;b2<6;b2++){
      int p2 = r0+b2;
      if(p2>=1 && p2<=16){
        #pragma unroll
        for(int o=0;o<4;o++){
          int c=g*4+o;
          h2S[c*108 + b2*18 + col+1] = fmaxf((float)aff2[2*c]*a24[o][b2] + (float)aff2[2*c+1], 0.f);
        }
      }
    }
  }
  __syncthreads();
  {
    int col = t & 15, og = t >> 4;
    float acc[8][4];
    #pragma unroll
    for(int o=0;o<8;o++){
      float bv = wf[WS_B3 + og*8 + o];
      #pragma unroll
      for(int r=0;r<4;r++) acc[o][r] = bv;
    }
    #pragma unroll 1
    for(int ic=0; ic<64; ++ic){
      float a[6][3];
      #pragma unroll
      for(int rr=0; rr<6; ++rr){
        #pragma unroll
        for(int dx=0; dx<3; ++dx) a[rr][dx] = h2S[ic*108 + rr*18 + col + dx];
      }
      const float* wrow = wf + WS_W3 + ic*1152;   // j-major layout (R18)
      #pragma unroll
      for(int o=0;o<8;o++){
        #pragma unroll
        for(int j=0;j<9;j++){
          float w = wrow[j*128 + og*8 + o];
          #pragma unroll
          for(int r=0;r<4;r++) acc[o][r] = fmaf(a[r + j/3][j%3], w, acc[o][r]);
        }
      }
    }
    #pragma unroll
    for(int o=0;o<8;o++){
      double s=0.0, q=0.0;
      #pragma unroll
      for(int r=0;r<4;r++){ double v=(double)acc[o][r]; s+=v; q+=v*v; }
      #pragma unroll
      for(int off=8; off; off>>=1){ s += __shfl_down(s, off, 16); q += __shfl_down(q, off, 16); }
      if(col==0){
        int c = og*8+o;
        atomicAdd(&acc3[(bid&63)*256 + c*2 + 0], s);
        atomicAdd(&acc3[(bid&63)*256 + c*2 + 1], q);
      }
    }
  }
}

// ========= FALLBACK recompute conv3 feat (f32, f64 accumulate), patches p0.. (dead) =========
__global__ __launch_bounds__(256) void k_p34(const float* __restrict__ x, const float* __restrict__ wf,
                                             const double* __restrict__ aff1, const double* __restrict__ aff2,
                                             const double* __restrict__ aff3, double* __restrict__ outp,
                                             int p0){
  __shared__ float xp[324];
  __shared__ float h1S[32*144];
  __shared__ float h2S[64*108];
  int bid=blockIdx.x, t=threadIdx.x;
  int p = p0 + (bid>>2), r0 = (bid&3)*4;
  for(int i=t;i<64*108;i+=256) h2S[i]=0.f;
  for(int i=t;i<324;i+=256) xp[i]=0.f;
  for(int i=t;i<32*144;i+=256) h1S[i]=0.f;
  __syncthreads();
  { int py=t>>4, px=t&15; xp[(py+1)*18 + px + 1] = x[(size_t)p*256+t]; }
  __syncthreads();
  {
    int rr=t>>5, cw=t&31, col=cw&15, half=cw>>4;
    int p1 = r0-1+rr;
    if(p1>=1 && p1<=16){
      float nb[9];
      #pragma unroll
      for(int j=0;j<9;j++) nb[j] = xp[(p1-1+j/3)*18 + col + (j%3)];
      for(int k=0;k<16;k++){
        int c = half*16+k;
        float a = wf[WS_B1+c];
        #pragma unroll
        for(int j=0;j<9;j++) a = fmaf(nb[j], wf[WS_W1+c*9+j], a);
        h1S[c*144 + rr*18 + col+1] = fmaxf((float)aff1[2*c]*a + (float)aff1[2*c+1], 0.f);
      }
    }
  }
  __syncthreads();
  {
    int col=t&15, g=t>>4;
    float a24[4][6];
    #pragma unroll
    for(int o=0;o<4;o++){
      float bv = wf[WS_B2+g*4+o];
      #pragma unroll
      for(int b2=0;b2<6;b2++) a24[o][b2] = bv;
    }
    #pragma unroll 1
    for(int ic=0;ic<32;ic++){
      const float* wrow = wf + WS_W2 + (g*4*32 + ic)*9;
      #pragma unroll
      for(int j=0;j<9;j++){
        float w4[4];
        #pragma unroll
        for(int o=0;o<4;o++) w4[o] = wrow[o*288 + j];
        int dy=j/3, dx=j%3;
        #pragma unroll
        for(int b2=0;b2<6;b2++){
          float m = h1S[ic*144 + (b2+dy)*18 + col + dx];
          #pragma unroll
          for(int o=0;o<4;o++) a24[o][b2] = fmaf(m, w4[o], a24[o][b2]);
        }
      }
    }
    #pragma unroll
    for(int b2=0;b2<6;b2++){
      int p2 = r0+b2;
      if(p2>=1 && p2<=16){
        #pragma unroll
        for(int o=0;o<4;o++){
          int c=g*4+o;
          h2S[c*108 + b2*18 + col+1] = fmaxf((float)aff2[2*c]*a24[o][b2] + (float)aff2[2*c+1], 0.f);
        }
      }
    }
  }
  __syncthreads();
  {
    int col = t & 15, og = t >> 4;
    float acc[8][4];
    #pragma unroll
    for(int o=0;o<8;o++){
      float bv = wf[WS_B3 + og*8 + o];
      #pragma unroll
      for(int r=0;r<4;r++) acc[o][r] = bv;
    }
    #pragma unroll 1
    for(int ic=0; ic<64; ++ic){
      float a[6][3];
      #pragma unroll
      for(int rr=0; rr<6; ++rr){
        #pragma unroll
        for(int dx=0; dx<3; ++dx) a[rr][dx] = h2S[ic*108 + rr*18 + col + dx];
      }
      const float* wrow = wf + WS_W3 + ic*1152;   // j-major layout (R18)
      #pragma unroll
      for(int o=0;o<8;o++){
        #pragma unroll
        for(int j=0;j<9;j++){
          float w = wrow[j*128 + og*8 + o];
          #pragma unroll
          for(int r=0;r<4;r++) acc[o][r] = fmaf(a[r + j/3][j%3], w, acc[o][r]);
        }
      }
    }
    #pragma unroll
    for(int o=0;o<8;o++){
      int c = og*8+o;
      float sc=(float)aff3[2*c], sh=(float)aff3[2*c+1];
      double s = 0.0;
      #pragma unroll
      for(int r=0;r<4;r++) s += (double)fmaxf(fmaf(sc, acc[o][r], sh), 0.f);
      #pragma unroll
      for(int off=8; off; off>>=1) s += __shfl_down(s, off, 16);
      if(col==0) atomicAdd(&outp[(size_t)p*128 + c], s);
    }
  }
}

// ---------------- LN + relu on [4][512] f64 LDS buffer ----------------
__device__ __forceinline__ void ln_relu4(double* buf, const float* __restrict__ g, const float* __restrict__ b,
                                         double* lnm, double* lnr, int t){
  int r=t>>6, j=t&63;
  double s=0.0, q=0.0;
  for(int k=j;k<512;k+=64){ double v=buf[r*512+k]; s+=v; q+=v*v; }
  #pragma unroll
  for(int off=32;off;off>>=1){ s+=__shfl_down(s,off); q+=__shfl_down(q,off); }
  if(j==0){
    double m = s*(1.0/512.0);
    double v = q*(1.0/512.0) - m*m;
    lnm[r]=m; lnr[r]=1.0/sqrt(v + 1e-5);
  }
  __syncthreads();
  for(int i=t;i<2048;i+=256){
    int r2=i>>9, k=i&511;
    double v=(buf[i]-lnm[r2])*lnr[r2]*(double)g[k]+(double)b[k];
    buf[i]=fmax(v,0.0);
  }
  __syncthreads();
}

// ---------------- MLP head (f64): feat -> assignment f32 (4 rows/block) ----------------
__global__ __launch_bounds__(256) void k_mlp(const float* __restrict__ wf, const double* __restrict__ feat,
                                             float* __restrict__ assign_out){
  int r0 = blockIdx.x*4, t = threadIdx.x;
  __shared__ double f0[4*128];
  __shared__ double f1[4*256];
  __shared__ double f2[4*512];
  __shared__ double f3[4*512];
  __shared__ double lnm[4], lnr[4];
  __shared__ double lg[4][8];

  for(int i=t;i<512;i+=256) f0[i] = feat[(size_t)r0*128 + i] * (1.0/256.0);
  __syncthreads();
  {
    double acc[4];
    double bv = (double)wf[WS_FCB + t];
    #pragma unroll
    for(int r=0;r<4;r++) acc[r]=bv;
    for(int k=0;k<128;k++){
      double wv = (double)wf[WS_FCW + t*128 + k];
      #pragma unroll
      for(int r=0;r<4;r++) acc[r]=fma(wv, f0[r*128+k], acc[r]);
    }
    #pragma unroll
    for(int r=0;r<4;r++) f1[r*256+t]=acc[r];
  }
  __syncthreads();
  for(int half=0;half<2;half++){
    int i=t+(half<<8);
    double acc[4];
    double bv=(double)wf[WS_G1B+i];
    #pragma unroll
    for(int r=0;r<4;r++) acc[r]=bv;
    for(int k=0;k<256;k++){
      double wv=(double)wf[WS_G1W + i*256 + k];
      #pragma unroll
      for(int r=0;r<4;r++) acc[r]=fma(wv, f1[r*256+k], acc[r]);
    }
    #pragma unroll
    for(int r=0;r<4;r++) f2[r*512+i]=acc[r];
  }
  __syncthreads();
  ln_relu4(f2, wf+WS_L1G, wf+WS_L1B, lnm, lnr, t);
  for(int half=0;half<2;half++){
    int i=t+(half<<8);
    double acc[4];
    double bv=(double)wf[WS_G2B+i];
    #pragma unroll
    for(int r=0;r<4;r++) acc[r]=bv;
    for(int k=0;k<512;k++){
      double wv=(double)wf[WS_G2W + i*512 + k];
      #pragma unroll
      for(int r=0;r<4;r++) acc[r]=fma(wv, f2[r*512+k], acc[r]);
    }
    #pragma unroll
    for(int r=0;r<4;r++) f3[r*512+i]=acc[r];
  }
  __syncthreads();
  ln_relu4(f3, wf+WS_L2G, wf+WS_L2B, lnm, lnr, t);
  {
    int r=t>>6, j=t&63;
    double pl[8];
    #pragma unroll
    for(int g=0;g<8;g++){
      double s=0.0;
      for(int k=j;k<512;k+=64) s = fma(f3[r*512+k], (double)wf[WS_G3W + g*512 + k], s);
      pl[g]=s;
    }
    #pragma unroll
    for(int off=32;off;off>>=1){
      #pragma unroll
      for(int g=0;g<8;g++) pl[g] += __shfl_down(pl[g], off);
    }
    if(j==0){
      #pragma unroll
      for(int g=0;g<8;g++) lg[r][g] = (pl[g] + (double)wf[WS_G3B+g]) * 2.0; // /TEMP
    }
  }
  __syncthreads();
  if(t<4){
    double m=-1e300;
    #pragma unroll
    for(int g=0;g<8;g++) m = fmax(m, lg[t][g]);
    double e[8], s=0.0;
    #pragma unroll
    for(int g=0;g<8;g++){ e[g]=exp(lg[t][g]-m); s+=e[g]; }
    double inv = 1.0/s;
    int row = r0 + t;
    #pragma unroll
    for(int g=0;g<8;g++) assign_out[row*8+g] = (float)(e[g]*inv);
  }
}

// ---------------- top-32 per (b,g) + gather*scale ----------------
__global__ __launch_bounds__(256) void k_topk(const float* __restrict__ assign, const float* __restrict__ x,
                                              float* __restrict__ out){
  int b = blockIdx.x >> 3, g = blockIdx.x & 7, t = threadIdx.x;
  __shared__ float v[256];
  __shared__ int   id[256];
  v[t] = assign[(b*256+t)*8 + g];
  id[t] = t;
  __syncthreads();
  for(int k=2;k<=256;k<<=1){
    for(int j=k>>1;j>0;j>>=1){
      int ixj = t ^ j;
      if(ixj > t){
        float va=v[t], vb=v[ixj];
        int ia=id[t], ib=id[ixj];
        bool aBefore = (va > vb) || (va == vb && ia < ib);
        bool up = ((t & k) == 0);
        if(up != aBefore){ v[t]=vb; v[ixj]=va; id[t]=ib; id[ixj]=ia; }
      }
      __syncthreads();
    }
  }
  __shared__ float tv[32];
  __shared__ int   ti[32];
  if(t<32){ tv[t]=v[t]; ti[t]=id[t]; }
  __syncthreads();
  const float* xb = x + (size_t)b*65536;
  float* ob = out + (size_t)(b*8+g)*8192;
  for(int i=t;i<8192;i+=256){
    int k=i>>8, pix=i&255;
    ob[i] = tv[k] * xb[ti[k]*256 + pix];
  }
}

// ---------------- launcher ----------------
extern "C" void kernel_launch(void* const* d_in, const int* in_sizes, int n_in,
                              void* d_out, int out_size, void* d_ws, size_t ws_size,
                              hipStream_t stream){
  const float* x = (const float*)d_in[0];
  float*  ws  = (float*)d_ws;
  double* dws = (double*)d_ws;
  float* out = (float*)d_out;
  float* assign_out = out + 1048576;
  float* z2 = (float*)((char*)d_ws + Z2_OFF_B);

  int nS = 0;
  if(ws_size > Z2_OFF_B + 65536){
    unsigned long long avail = (unsigned long long)ws_size - Z2_OFF_B;
    unsigned long long n = avail / 65536ull;
    nS = (n > 4096ull) ? 4096 : (int)n;
  }
  int nR = 4096 - nS;

  const float* g1=(const float*)d_in[3];  const float* b1=(const float*)d_in[4];
  const float* g2=(const float*)d_in[7];  const float* b2=(const float*)d_in[8];
  const float* g3=(const float*)d_in[11]; const float* b3=(const float*)d_in[12];

  WP wp;
  const int map[18] = {1,2,5,6,9,10,13,14,15,16,17,18,19,20,21,22,23,24};
  for(int i=0;i<18;i++) wp.p[i] = (const float*)d_in[map[i]];

  k_zero <<<2162, 256, 0, stream>>>(dws + D_ACC1);
  k_cvt  <<<dim3(1024,19), 256, 0, stream>>>(wp, ws);
  k_p1   <<<4096, 256, 0, stream>>>(x, ws, dws+D_ACC1);
  k_fin  <<<32, 64, 0, stream>>>(dws+D_ACC1, 32, g1, b1, dws+D_AFF1);
  k_p2   <<<4096, 256, 0, stream>>>(x, ws, dws+D_AFF1, dws+D_ACC2, z2, nS);
  k_fin  <<<64, 64, 0, stream>>>(dws+D_ACC2, 64, g2, b2, dws+D_AFF2);
  if(nS > 0) k_cs   <<<2*nS, 512, 0, stream>>>(ws, dws+D_AFF2, dws+D_ACC3, z2);
  if(nR > 0) k_stat3<<<4*nR, 256, 0, stream>>>(x, ws, dws+D_AFF1, dws+D_AFF2, dws+D_ACC3, nS);
  k_fin  <<<128, 64, 0, stream>>>(dws+D_ACC3, 128, g3, b3, dws+D_AFF3);
  if(nS > 0) k_cf  <<<2*nS, 512, 0, stream>>>(ws, dws+D_AFF2, dws+D_AFF3, dws+D_FEAT, z2);
  if(nR > 0) k_p34 <<<4*nR, 256, 0, stream>>>(x, ws, dws+D_AFF1, dws+D_AFF2, dws+D_AFF3, dws+D_FEAT, nS);
  k_mlp  <<<1024, 256, 0, stream>>>(ws, dws+D_FEAT, assign_out);
  k_topk <<<128, 256, 0, stream>>>(assign_out, x, out);
}